// Round 1
// baseline (1489.110 us; speedup 1.0000x reference)
//
#include <hip/hip_runtime.h>

// Problem constants
#define SEQ   2048
#define DIM   400
#define HSZ   100
#define SCALE_F 0.1f

// ws layout (float offsets)
#define WS_WQ   0L
#define WS_WK   3276800L       // 32768*100
#define WS_WV   6553600L
#define WS_VO   9830400L
#define WS_ADF  13107200L      // 100*400
#define WS_W2   13147200L      // 100*400
#define WS_PMAX 13187200L      // 16*64*400
#define WS_PSUM 13596800L
#define WS_POOL 14006400L      // 16*800
#define WS_FC1  14019200L      // 16*512

// ---------------- fold attn_dense: AD_f[h][e] = sum_k ad[k*100+h][e] -------
__global__ void k_fold(const float* __restrict__ ad, float* __restrict__ adf) {
    int i = blockIdx.x * 256 + threadIdx.x;
    if (i < 100 * 400) {
        int h = i / 400, e = i % 400;
        float s = 0.f;
        #pragma unroll
        for (int k = 0; k < 4; ++k) s += ad[(k * 100 + h) * 400 + e];
        adf[i] = s;
    }
}

// ---------------- W2[h][j] = sum_e AD_f[h][e] * d1_w[e][j] -----------------
__global__ void k_w2(const float* __restrict__ adf, const float* __restrict__ d1w,
                     float* __restrict__ w2) {
    int i = blockIdx.x * 256 + threadIdx.x;
    if (i < 100 * 400) {
        int h = i / 400, j = i % 400;
        float acc = 0.f;
        for (int e = 0; e < 400; ++e) acc += adf[h * 400 + e] * d1w[e * 400 + j];
        w2[i] = acc;
    }
}

// ---------------- QKV: out[m] = x @ attn_kernel[m], [32768,400]x[400,100] --
// grid (1024, 3), block 256. 32 rows per block staged in LDS.
__global__ __launch_bounds__(256) void k_qkv(const float* __restrict__ x,
                                             const float* __restrict__ wk_all,
                                             float* __restrict__ ws) {
    __shared__ float xs[32 * 400];
    const int tid = threadIdx.x;
    const int m = blockIdx.y;
    const long row0 = (long)blockIdx.x * 32;
    const float* xb = x + row0 * 400;
    for (int e = tid; e < 12800; e += 256) xs[e] = xb[e];
    __syncthreads();

    const int tx = tid & 31, ty = tid >> 5;
    if (tx >= 25) return;                    // 25*4 = 100 output cols, no syncs after
    const int h4 = tx * 4;
    const float* __restrict__ W = wk_all + m * 40000;
    float* __restrict__ out = ws + (long)m * 3276800L + row0 * 100;

    float acc[4][4] = {};
    for (int d = 0; d < 400; d += 2) {
        float4 wa = *(const float4*)&W[d * 100 + h4];
        float4 wb = *(const float4*)&W[(d + 1) * 100 + h4];
        #pragma unroll
        for (int i = 0; i < 4; ++i) {
            float2 xv = *(const float2*)&xs[(ty * 4 + i) * 400 + d];
            acc[i][0] += xv.x * wa.x + xv.y * wb.x;
            acc[i][1] += xv.x * wa.y + xv.y * wb.y;
            acc[i][2] += xv.x * wa.z + xv.y * wb.z;
            acc[i][3] += xv.x * wa.w + xv.y * wb.w;
        }
    }
    #pragma unroll
    for (int i = 0; i < 4; ++i) {
        *(float4*)&out[(ty * 4 + i) * 100 + h4] =
            make_float4(acc[i][0], acc[i][1], acc[i][2], acc[i][3]);
    }
}

// ---------------- flash attention (f32): per (b, 64-row q-tile) ------------
// grid (32, 16), block 256. KV tile = 32. Online softmax.
__global__ __launch_bounds__(256) void k_flash(const float* __restrict__ wq,
                                               const float* __restrict__ wk,
                                               const float* __restrict__ wv,
                                               float* __restrict__ vo) {
    __shared__ float Qs[64 * 100];        // row-major, broadcast reads
    __shared__ float Ks[32 * 102];        // pad 102: conflict-free b64
    __shared__ float VsT[100 * 33];       // d-major, pad 33
    __shared__ float Ss[64 * 33];         // pad 33
    __shared__ float m_s[64], l_s[64], sc_s[64];

    const int tid = threadIdx.x;
    const int b = blockIdx.y, qt = blockIdx.x;
    const float* Wqb = wq + ((long)b * SEQ + qt * 64) * 100;
    const float* Wkb = wk + (long)b * SEQ * 100;
    const float* Wvb = wv + (long)b * SEQ * 100;

    for (int e = tid; e < 6400; e += 256) Qs[e] = Wqb[e];
    if (tid < 64) { m_s[tid] = -1e30f; l_s[tid] = 0.f; }

    const int kg = tid & 15;   // S-phase: k-pair 2kg,2kg+1
    const int qg = tid >> 4;   // S-phase: q rows qg*4..+3
    const int jg = tid & 15;   // PV: d = jg*7..+6
    const int qp = tid >> 4;   // PV: q rows qp*4..+3

    float O[4][7] = {};

    for (int it = 0; it < 64; ++it) {
        __syncthreads();   // prev PV done before K/V overwrite (also covers init)
        const float* Kt = Wkb + it * 3200;
        const float* Vt = Wvb + it * 3200;
        for (int e = tid; e < 3200; e += 256) {
            int r = e / 100, d = e % 100;
            Ks[r * 102 + d] = Kt[e];
            VsT[d * 33 + r] = Vt[e];
        }
        __syncthreads();

        // ---- S = Q K^T  (each thread: 4q x 2k dots of length 100)
        float s[4][2] = {};
        for (int d = 0; d < 100; d += 2) {
            float2 k0 = *(const float2*)&Ks[(2 * kg) * 102 + d];
            float2 k1 = *(const float2*)&Ks[(2 * kg + 1) * 102 + d];
            #pragma unroll
            for (int i = 0; i < 4; ++i) {
                float2 qv = *(const float2*)&Qs[(qg * 4 + i) * 100 + d];
                s[i][0] += qv.x * k0.x + qv.y * k0.y;
                s[i][1] += qv.x * k1.x + qv.y * k1.y;
            }
        }
        #pragma unroll
        for (int i = 0; i < 4; ++i) {
            Ss[(qg * 4 + i) * 33 + 2 * kg]     = s[i][0];
            Ss[(qg * 4 + i) * 33 + 2 * kg + 1] = s[i][1];
        }
        __syncthreads();

        // ---- online softmax (4 threads per q-row, 8 cols each)
        {
            const int q = tid >> 2, j = tid & 3;
            float sv[8], mx = -1e30f;
            #pragma unroll
            for (int i = 0; i < 8; ++i) {
                sv[i] = Ss[q * 33 + j * 8 + i] * SCALE_F;
                mx = fmaxf(mx, sv[i]);
            }
            mx = fmaxf(mx, __shfl_xor(mx, 1));
            mx = fmaxf(mx, __shfl_xor(mx, 2));
            const float m_old = m_s[q];
            const float m_new = fmaxf(m_old, mx);
            float sum = 0.f;
            #pragma unroll
            for (int i = 0; i < 8; ++i) {
                float p = __expf(sv[i] - m_new);
                sum += p;
                Ss[q * 33 + j * 8 + i] = p;
            }
            sum += __shfl_xor(sum, 1);
            sum += __shfl_xor(sum, 2);
            if (j == 0) {
                sc_s[q] = __expf(m_old - m_new);
                m_s[q] = m_new;
                l_s[q] = l_s[q] * sc_s[q] + sum;
            }
        }
        __syncthreads();

        // ---- PV accumulate: O[q][d] = O*sc + sum_k P[q][k] V[k][d]
        #pragma unroll
        for (int c = 0; c < 4; ++c) {
            float sc = sc_s[qp * 4 + c];
            #pragma unroll
            for (int i = 0; i < 7; ++i) O[c][i] *= sc;
        }
        for (int k = 0; k < 32; ++k) {
            float p[4];
            #pragma unroll
            for (int c = 0; c < 4; ++c) p[c] = Ss[(qp * 4 + c) * 33 + k];
            #pragma unroll
            for (int i = 0; i < 7; ++i) {
                int d = jg * 7 + i;
                if (d < 100) {
                    float v = VsT[d * 33 + k];
                    O[0][i] += p[0] * v;
                    O[1][i] += p[1] * v;
                    O[2][i] += p[2] * v;
                    O[3][i] += p[3] * v;
                }
            }
        }
    }

    // ---- normalize and store
    float* vob = vo + ((long)b * SEQ + qt * 64) * 100;
    #pragma unroll
    for (int c = 0; c < 4; ++c) {
        int q = qp * 4 + c;
        float inv = 1.f / l_s[q];
        #pragma unroll
        for (int i = 0; i < 7; ++i) {
            int d = jg * 7 + i;
            if (d < 100) vob[q * 100 + d] = O[c][i] * inv;
        }
    }
}

// ---------------- h = relu(V@W2 + d1_b); partial max/sum pool --------------
// grid (64, 16), block 256. 32 rows per block.
__global__ __launch_bounds__(256) void k_hpool(const float* __restrict__ vo,
                                               const float* __restrict__ w2,
                                               const float* __restrict__ d1b,
                                               float* __restrict__ pmax,
                                               float* __restrict__ psum) {
    __shared__ float Vt[32 * 100];
    __shared__ float red[2][8][128];
    const int tid = threadIdx.x;
    const int b = blockIdx.y, rt = blockIdx.x;
    const float* vb = vo + ((long)b * SEQ + rt * 32) * 100;
    for (int e = tid; e < 3200; e += 256) Vt[e] = vb[e];
    __syncthreads();

    const int tx = tid & 31, ty = tid >> 5;
    for (int pass = 0; pass < 4; ++pass) {
        int jq = pass * 32 + tx;           // col-quad index, active < 100
        bool act = (jq < 100);
        if (act) {
            int j4 = jq * 4;
            float4 bias = *(const float4*)&d1b[j4];
            float acc[4][4];
            #pragma unroll
            for (int i = 0; i < 4; ++i) {
                acc[i][0] = bias.x; acc[i][1] = bias.y;
                acc[i][2] = bias.z; acc[i][3] = bias.w;
            }
            for (int d = 0; d < 100; d += 2) {
                float4 wa = *(const float4*)&w2[d * 400 + j4];
                float4 wb = *(const float4*)&w2[(d + 1) * 400 + j4];
                #pragma unroll
                for (int i = 0; i < 4; ++i) {
                    float2 xv = *(const float2*)&Vt[(ty * 4 + i) * 100 + d];
                    acc[i][0] += xv.x * wa.x + xv.y * wb.x;
                    acc[i][1] += xv.x * wa.y + xv.y * wb.y;
                    acc[i][2] += xv.x * wa.z + xv.y * wb.z;
                    acc[i][3] += xv.x * wa.w + xv.y * wb.w;
                }
            }
            #pragma unroll
            for (int c = 0; c < 4; ++c) {
                float h0 = fmaxf(acc[0][c], 0.f), h1 = fmaxf(acc[1][c], 0.f);
                float h2 = fmaxf(acc[2][c], 0.f), h3 = fmaxf(acc[3][c], 0.f);
                red[0][ty][tx * 4 + c] = fmaxf(fmaxf(h0, h1), fmaxf(h2, h3));
                red[1][ty][tx * 4 + c] = h0 + h1 + h2 + h3;
            }
        }
        __syncthreads();
        if (tid < 128) {
            int jgl = pass * 128 + tid;
            if (jgl < 400) {
                float mx = red[0][0][tid], sm = red[1][0][tid];
                #pragma unroll
                for (int t = 1; t < 8; ++t) {
                    mx = fmaxf(mx, red[0][t][tid]);
                    sm += red[1][t][tid];
                }
                pmax[((long)b * 64 + rt) * 400 + jgl] = mx;
                psum[((long)b * 64 + rt) * 400 + jgl] = sm;
            }
        }
        __syncthreads();
    }
}

// ---------------- reduce partials -> pooled[b][800] ------------------------
__global__ void k_pred(const float* __restrict__ pmax, const float* __restrict__ psum,
                       float* __restrict__ pooled) {
    const int b = blockIdx.x;
    for (int j = threadIdx.x; j < 400; j += 256) {
        float mx = -1e30f, sm = 0.f;
        for (int t = 0; t < 64; ++t) {
            mx = fmaxf(mx, pmax[((long)b * 64 + t) * 400 + j]);
            sm += psum[((long)b * 64 + t) * 400 + j];
        }
        pooled[b * 800 + j] = mx;
        pooled[b * 800 + 400 + j] = sm * (1.f / 2048.f);
    }
}

// ---------------- fc1: [16,800]x[800,512] + relu ---------------------------
__global__ void k_fc1(const float* __restrict__ pooled, const float* __restrict__ w,
                      const float* __restrict__ bias, float* __restrict__ out) {
    const int b = blockIdx.x, j = threadIdx.x;
    float acc = bias[j];
    for (int k = 0; k < 800; ++k) acc += pooled[b * 800 + k] * w[k * 512 + j];
    out[b * 512 + j] = fmaxf(acc, 0.f);
}

// ---------------- fc2: [16,512]x[512,256] + relu ---------------------------
__global__ void k_fc2(const float* __restrict__ h, const float* __restrict__ w,
                      const float* __restrict__ bias, float* __restrict__ out) {
    const int b = blockIdx.x, j = threadIdx.x;
    float acc = bias[j];
    for (int k = 0; k < 512; ++k) acc += h[b * 512 + k] * w[k * 256 + j];
    out[b * 256 + j] = fmaxf(acc, 0.f);
}

extern "C" void kernel_launch(void* const* d_in, const int* in_sizes, int n_in,
                              void* d_out, int out_size, void* d_ws, size_t ws_size,
                              hipStream_t stream) {
    const float* x          = (const float*)d_in[0];
    const float* attn_kernel= (const float*)d_in[1];
    const float* attn_dense = (const float*)d_in[2];
    const float* d1_w       = (const float*)d_in[3];
    const float* d1_b       = (const float*)d_in[4];
    const float* fc1_w      = (const float*)d_in[5];
    const float* fc1_b      = (const float*)d_in[6];
    const float* fc2_w      = (const float*)d_in[7];
    const float* fc2_b      = (const float*)d_in[8];
    float* out = (float*)d_out;
    float* ws  = (float*)d_ws;

    k_fold<<<157, 256, 0, stream>>>(attn_dense, ws + WS_ADF);
    k_w2  <<<157, 256, 0, stream>>>(ws + WS_ADF, d1_w, ws + WS_W2);
    k_qkv <<<dim3(1024, 3), 256, 0, stream>>>(x, attn_kernel, ws);
    k_flash<<<dim3(32, 16), 256, 0, stream>>>(ws + WS_WQ, ws + WS_WK, ws + WS_WV, ws + WS_VO);
    k_hpool<<<dim3(64, 16), 256, 0, stream>>>(ws + WS_VO, ws + WS_W2, d1_b,
                                              ws + WS_PMAX, ws + WS_PSUM);
    k_pred<<<16, 256, 0, stream>>>(ws + WS_PMAX, ws + WS_PSUM, ws + WS_POOL);
    k_fc1 <<<16, 512, 0, stream>>>(ws + WS_POOL, fc1_w, fc1_b, ws + WS_FC1);
    k_fc2 <<<16, 256, 0, stream>>>(ws + WS_FC1, fc2_w, fc2_b, out);
}

// Round 2
// 555.920 us; speedup vs baseline: 2.6786x; 2.6786x over previous
//
#include <hip/hip_runtime.h>

typedef __attribute__((ext_vector_type(8))) short bf8v;   // 8 bf16 (4 VGPRs)
typedef __attribute__((ext_vector_type(4))) float f4v;    // MFMA accumulator
typedef unsigned short u16;

__device__ __forceinline__ u16 f2bf(float f) {            // f32 -> bf16 RNE
    unsigned int u = __builtin_bit_cast(unsigned int, f);
    u += 0x7fffu + ((u >> 16) & 1u);
    return (u16)(u >> 16);
}

// ---------------- fold attn_dense: AD_f[h][e] = sum_k ad[k*100+h][e] -------
__global__ void k_fold(const float* __restrict__ ad, float* __restrict__ adf) {
    int i = blockIdx.x * 256 + threadIdx.x;
    if (i < 100 * 400) {
        int h = i / 400, e = i % 400;
        float s = 0.f;
        #pragma unroll
        for (int k = 0; k < 4; ++k) s += ad[(k * 100 + h) * 400 + e];
        adf[i] = s;
    }
}

// ---------------- W2[h][j] = sum_e AD_f[h][e] * d1_w[e][j] -----------------
__global__ void k_w2(const float* __restrict__ adf, const float* __restrict__ d1w,
                     float* __restrict__ w2) {
    int i = blockIdx.x * 256 + threadIdx.x;
    if (i < 100 * 400) {
        int h = i / 400, j = i % 400;
        float acc = 0.f;
        for (int e = 0; e < 400; ++e) acc += adf[h * 400 + e] * d1w[e * 400 + j];
        w2[i] = acc;
    }
}

// ---------------- QKV projection (f32 math, bf16 outputs, D padded to 128) -
// grid (1024, 3), block 256. m=0 -> Qhi; m=1 -> Khi+Klo split; m=2 -> Vb.
__global__ __launch_bounds__(256) void k_qkv(const float* __restrict__ x,
                                             const float* __restrict__ wk_all,
                                             u16* __restrict__ Qhi,
                                             u16* __restrict__ Khi,
                                             u16* __restrict__ Klo,
                                             u16* __restrict__ Vb) {
    __shared__ float xs[32 * 400];
    const int tid = threadIdx.x;
    const int m = blockIdx.y;
    const long row0 = (long)blockIdx.x * 32;
    const float* xb = x + row0 * 400;
    for (int e = tid; e < 12800; e += 256) xs[e] = xb[e];
    __syncthreads();

    const int tx = tid & 31, ty = tid >> 5;
    if (tx >= 25) return;                    // 25*4 = 100 output cols
    const int h4 = tx * 4;
    const float* __restrict__ W = wk_all + m * 40000;

    float acc[4][4] = {};
    for (int d = 0; d < 400; d += 2) {
        float4 wa = *(const float4*)&W[d * 100 + h4];
        float4 wb = *(const float4*)&W[(d + 1) * 100 + h4];
        #pragma unroll
        for (int i = 0; i < 4; ++i) {
            float2 xv = *(const float2*)&xs[(ty * 4 + i) * 400 + d];
            acc[i][0] += xv.x * wa.x + xv.y * wb.x;
            acc[i][1] += xv.x * wa.y + xv.y * wb.y;
            acc[i][2] += xv.x * wa.z + xv.y * wb.z;
            acc[i][3] += xv.x * wa.w + xv.y * wb.w;
        }
    }
    #pragma unroll
    for (int i = 0; i < 4; ++i) {
        long row = row0 + ty * 4 + i;
        if (m == 0) {
            ushort4 hv;
            hv.x = f2bf(acc[i][0]); hv.y = f2bf(acc[i][1]);
            hv.z = f2bf(acc[i][2]); hv.w = f2bf(acc[i][3]);
            *(ushort4*)&Qhi[row * 128 + h4] = hv;
        } else if (m == 1) {
            ushort4 hv, lv;
            #pragma unroll
            for (int c = 0; c < 4; ++c) {
                float v = acc[i][c];
                u16 hb = f2bf(v);
                float hf = __builtin_bit_cast(float, (unsigned int)hb << 16);
                u16 lb = f2bf(v - hf);
                ((u16*)&hv)[c] = hb;
                ((u16*)&lv)[c] = lb;
            }
            *(ushort4*)&Khi[row * 128 + h4] = hv;
            *(ushort4*)&Klo[row * 128 + h4] = lv;
        } else {
            ushort4 hv;
            hv.x = f2bf(acc[i][0]); hv.y = f2bf(acc[i][1]);
            hv.z = f2bf(acc[i][2]); hv.w = f2bf(acc[i][3]);
            *(ushort4*)&Vb[row * 128 + h4] = hv;
        }
    }
}

// ---------------- MFMA flash attention -------------------------------------
// grid (32, 16), block 256 (4 waves x 16 q-rows). KV tile 64, D padded 128.
// S = Qhi*Khi + Qhi*Klo (split-K bf16, ~16 mantissa bits in logits).
__global__ __launch_bounds__(256) void k_flash_mfma(
    const u16* __restrict__ Qg, const u16* __restrict__ Khig,
    const u16* __restrict__ Klog, const u16* __restrict__ Vg,
    float* __restrict__ vo) {
    __shared__ __align__(16) char KhiS[16384];     // [64 keys][128 d] swizzled
    __shared__ __align__(16) char KloS[16384];
    __shared__ __align__(16) char VtS[16384];      // [128 d][64 k] swizzled
    __shared__ __align__(16) char PS[4][2048];     // per-wave P [16 q][64 k]

    const int tid = threadIdx.x;
    const int w = tid >> 6;
    const int l = tid & 63;
    const int c15 = l & 15;
    const int g = l >> 4;
    const int b = blockIdx.y, qt = blockIdx.x;

    const long bbase = (long)b * 2048 * 128;
    const u16* qp = Qg + bbase + (long)(qt * 64 + w * 16 + c15) * 128;

    // A-frags for Q: lane holds Q[row=c15][k = ks*32 + g*8 + j]
    bf8v qh[4];
    #pragma unroll
    for (int ks = 0; ks < 4; ++ks) qh[ks] = *(const bf8v*)(qp + ks * 32 + g * 8);

    f4v O[7];
    #pragma unroll
    for (int i = 0; i < 7; ++i) O[i] = (f4v){0.f, 0.f, 0.f, 0.f};
    float mrow[4] = {-1e30f, -1e30f, -1e30f, -1e30f};
    float lrow[4] = {0.f, 0.f, 0.f, 0.f};

    const u16* Khb = Khig + bbase;
    const u16* Klb = Klog + bbase;
    const u16* Vgb = Vg + bbase;
    char* Pw = PS[w];

    for (int t = 0; t < 32; ++t) {
        __syncthreads();                            // prev compute done
        // ---- stage Khi/Klo, XOR-swizzled rows (chunk c of row -> c^(row&7))
        #pragma unroll
        for (int r = 0; r < 4; ++r) {
            int u = tid + r * 256;                  // 1024 16B-chunks per array
            int row = u >> 4, c = u & 15;
            long gs = (long)(t * 64 + row) * 128 + c * 8;
            int dst = row * 256 + ((c * 16) ^ ((row & 7) << 4));
            *(bf8v*)(KhiS + dst) = *(const bf8v*)(Khb + gs);
            *(bf8v*)(KloS + dst) = *(const bf8v*)(Klb + gs);
        }
        // ---- stage V transposed: Vt[d][k], packed k-pairs, swizzled
        #pragma unroll
        for (int r = 0; r < 2; ++r) {
            int u = tid + r * 256;                  // 512 units: kpair x d-chunk
            int kp = u >> 4, c = u & 15;
            const u16* v0 = Vgb + (long)(t * 64 + kp * 2) * 128 + c * 8;
            bf8v va = *(const bf8v*)(v0);
            bf8v vb2 = *(const bf8v*)(v0 + 128);
            #pragma unroll
            for (int j = 0; j < 8; ++j) {
                int d = c * 8 + j;
                unsigned int val = (unsigned int)(u16)va[j] |
                                   ((unsigned int)(u16)vb2[j] << 16);
                *(unsigned int*)(VtS + d * 128 + ((kp * 4) ^ ((d & 7) << 4))) = val;
            }
        }
        __syncthreads();                            // staged (barrier drains vmcnt)

        // ---- QK^T: S[16q x 64k] in C-layout (col=c15=key, row=g*4+r=q)
        f4v s[4];
        #pragma unroll
        for (int nt = 0; nt < 4; ++nt) s[nt] = (f4v){0.f, 0.f, 0.f, 0.f};
        #pragma unroll
        for (int ks = 0; ks < 4; ++ks) {
            #pragma unroll
            for (int nt = 0; nt < 4; ++nt) {
                int key = nt * 16 + c15;
                int off = key * 256 + ((ks * 64 + g * 16) ^ ((key & 7) << 4));
                bf8v kh = *(const bf8v*)(KhiS + off);
                bf8v kl = *(const bf8v*)(KloS + off);
                s[nt] = __builtin_amdgcn_mfma_f32_16x16x32_bf16(qh[ks], kh, s[nt], 0, 0, 0);
                s[nt] = __builtin_amdgcn_mfma_f32_16x16x32_bf16(qh[ks], kl, s[nt], 0, 0, 0);
            }
        }

        // ---- online softmax: per C-register r (=row g*4+r), reduce over c15
        float sc[4];
        #pragma unroll
        for (int r = 0; r < 4; ++r) {
            float mx = fmaxf(fmaxf(s[0][r], s[1][r]), fmaxf(s[2][r], s[3][r]));
            mx = fmaxf(mx, __shfl_xor(mx, 1));
            mx = fmaxf(mx, __shfl_xor(mx, 2));
            mx = fmaxf(mx, __shfl_xor(mx, 4));
            mx = fmaxf(mx, __shfl_xor(mx, 8));
            float mnew = fmaxf(mrow[r], mx * 0.1f);
            sc[r] = __expf(mrow[r] - mnew);
            mrow[r] = mnew;
            float sum = 0.f;
            #pragma unroll
            for (int nt = 0; nt < 4; ++nt) {
                float p = __expf(s[nt][r] * 0.1f - mnew);
                s[nt][r] = p;
                sum += p;
            }
            sum += __shfl_xor(sum, 1);
            sum += __shfl_xor(sum, 2);
            sum += __shfl_xor(sum, 4);
            sum += __shfl_xor(sum, 8);
            lrow[r] = lrow[r] * sc[r] + sum;
        }
        // ---- P -> per-wave swizzled LDS (bf16), for PV A-frag re-layout
        #pragma unroll
        for (int nt = 0; nt < 4; ++nt) {
            #pragma unroll
            for (int r = 0; r < 4; ++r) {
                int q = g * 4 + r;
                *(u16*)(Pw + q * 128 + ((nt * 32 + c15 * 2) ^ ((q & 7) << 4))) =
                    f2bf(s[nt][r]);
            }
        }
        // ---- rescale O
        #pragma unroll
        for (int dt = 0; dt < 7; ++dt) {
            #pragma unroll
            for (int r = 0; r < 4; ++r) O[dt][r] *= sc[r];
        }
        // ---- PV: O[16q][112d] += P[16q][64k] * V[64k][d]
        #pragma unroll
        for (int k0 = 0; k0 < 2; ++k0) {
            bf8v pa = *(const bf8v*)(Pw + c15 * 128 +
                                     ((k0 * 64 + g * 16) ^ ((c15 & 7) << 4)));
            #pragma unroll
            for (int dt = 0; dt < 7; ++dt) {
                int d = dt * 16 + c15;
                bf8v vf = *(const bf8v*)(VtS + d * 128 +
                                         ((k0 * 64 + g * 16) ^ ((d & 7) << 4)));
                O[dt] = __builtin_amdgcn_mfma_f32_16x16x32_bf16(pa, vf, O[dt], 0, 0, 0);
            }
        }
    }

    // ---- normalize + store (C-layout: row = g*4+r, col d = dt*16+c15)
    const long qbase = (long)b * 2048 + qt * 64 + w * 16 + g * 4;
    #pragma unroll
    for (int r = 0; r < 4; ++r) {
        float inv = 1.f / lrow[r];
        #pragma unroll
        for (int dt = 0; dt < 7; ++dt) {
            int d = dt * 16 + c15;
            if (d < 100) vo[(qbase + r) * 100 + d] = O[dt][r] * inv;
        }
    }
}

// ---------------- h = relu(V@W2 + d1_b); partial max/sum pool --------------
__global__ __launch_bounds__(256) void k_hpool(const float* __restrict__ vo,
                                               const float* __restrict__ w2,
                                               const float* __restrict__ d1b,
                                               float* __restrict__ pmax,
                                               float* __restrict__ psum) {
    __shared__ float Vt[32 * 100];
    __shared__ float red[2][8][128];
    const int tid = threadIdx.x;
    const int b = blockIdx.y, rt = blockIdx.x;
    const float* vb = vo + ((long)b * 2048 + rt * 32) * 100;
    for (int e = tid; e < 3200; e += 256) Vt[e] = vb[e];
    __syncthreads();

    const int tx = tid & 31, ty = tid >> 5;
    for (int pass = 0; pass < 4; ++pass) {
        int jq = pass * 32 + tx;
        bool act = (jq < 100);
        if (act) {
            int j4 = jq * 4;
            float4 bias = *(const float4*)&d1b[j4];
            float acc[4][4];
            #pragma unroll
            for (int i = 0; i < 4; ++i) {
                acc[i][0] = bias.x; acc[i][1] = bias.y;
                acc[i][2] = bias.z; acc[i][3] = bias.w;
            }
            for (int d = 0; d < 100; d += 2) {
                float4 wa = *(const float4*)&w2[d * 400 + j4];
                float4 wb = *(const float4*)&w2[(d + 1) * 400 + j4];
                #pragma unroll
                for (int i = 0; i < 4; ++i) {
                    float2 xv = *(const float2*)&Vt[(ty * 4 + i) * 100 + d];
                    acc[i][0] += xv.x * wa.x + xv.y * wb.x;
                    acc[i][1] += xv.x * wa.y + xv.y * wb.y;
                    acc[i][2] += xv.x * wa.z + xv.y * wb.z;
                    acc[i][3] += xv.x * wa.w + xv.y * wb.w;
                }
            }
            #pragma unroll
            for (int c = 0; c < 4; ++c) {
                float h0 = fmaxf(acc[0][c], 0.f), h1 = fmaxf(acc[1][c], 0.f);
                float h2 = fmaxf(acc[2][c], 0.f), h3 = fmaxf(acc[3][c], 0.f);
                red[0][ty][tx * 4 + c] = fmaxf(fmaxf(h0, h1), fmaxf(h2, h3));
                red[1][ty][tx * 4 + c] = h0 + h1 + h2 + h3;
            }
        }
        __syncthreads();
        if (tid < 128) {
            int jgl = pass * 128 + tid;
            if (jgl < 400) {
                float mx = red[0][0][tid], sm = red[1][0][tid];
                #pragma unroll
                for (int t = 1; t < 8; ++t) {
                    mx = fmaxf(mx, red[0][t][tid]);
                    sm += red[1][t][tid];
                }
                pmax[((long)b * 64 + rt) * 400 + jgl] = mx;
                psum[((long)b * 64 + rt) * 400 + jgl] = sm;
            }
        }
        __syncthreads();
    }
}

// ---------------- reduce partials -> pooled[b][800] ------------------------
__global__ void k_pred(const float* __restrict__ pmax, const float* __restrict__ psum,
                       float* __restrict__ pooled) {
    const int b = blockIdx.x;
    for (int j = threadIdx.x; j < 400; j += 256) {
        float mx = -1e30f, sm = 0.f;
        for (int t = 0; t < 64; ++t) {
            mx = fmaxf(mx, pmax[((long)b * 64 + t) * 400 + j]);
            sm += psum[((long)b * 64 + t) * 400 + j];
        }
        pooled[b * 800 + j] = mx;
        pooled[b * 800 + 400 + j] = sm * (1.f / 2048.f);
    }
}

// ---------------- fc1 / fc2 ------------------------------------------------
__global__ void k_fc1(const float* __restrict__ pooled, const float* __restrict__ w,
                      const float* __restrict__ bias, float* __restrict__ out) {
    const int b = blockIdx.x, j = threadIdx.x;
    float acc = bias[j];
    for (int k = 0; k < 800; ++k) acc += pooled[b * 800 + k] * w[k * 512 + j];
    out[b * 512 + j] = fmaxf(acc, 0.f);
}

__global__ void k_fc2(const float* __restrict__ h, const float* __restrict__ w,
                      const float* __restrict__ bias, float* __restrict__ out) {
    const int b = blockIdx.x, j = threadIdx.x;
    float acc = bias[j];
    for (int k = 0; k < 512; ++k) acc += h[b * 512 + k] * w[k * 256 + j];
    out[b * 256 + j] = fmaxf(acc, 0.f);
}

extern "C" void kernel_launch(void* const* d_in, const int* in_sizes, int n_in,
                              void* d_out, int out_size, void* d_ws, size_t ws_size,
                              hipStream_t stream) {
    const float* x          = (const float*)d_in[0];
    const float* attn_kernel= (const float*)d_in[1];
    const float* attn_dense = (const float*)d_in[2];
    const float* d1_w       = (const float*)d_in[3];
    const float* d1_b       = (const float*)d_in[4];
    const float* fc1_w      = (const float*)d_in[5];
    const float* fc1_b      = (const float*)d_in[6];
    const float* fc2_w      = (const float*)d_in[7];
    const float* fc2_b      = (const float*)d_in[8];
    float* out = (float*)d_out;
    float* ws  = (float*)d_ws;
    char*  wsb = (char*)d_ws;

    // ws layout (bytes): VO f32 [0,13107200) | bf16 QHI/KHI/KLO/VB 4x8MB
    // [13107200,46661632) | f32 tail. Total ~50.3 MB (< 56.1 MB proven OK).
    float* VO   = ws;
    u16*   QHI  = (u16*)(wsb + 13107200);
    u16*   KHI  = QHI + 4194304;
    u16*   KLO  = KHI + 4194304;
    u16*   VB   = KLO + 4194304;
    float* ADF  = ws + 11665408;
    float* W2   = ws + 11705408;
    float* PMAX = ws + 11745408;
    float* PSUM = ws + 12155008;
    float* POOL = ws + 12564608;
    float* FC1  = ws + 12577408;

    hipMemsetAsync(wsb + 13107200, 0, 33554432, stream);   // zero-pad D 100..127

    k_fold<<<157, 256, 0, stream>>>(attn_dense, ADF);
    k_w2  <<<157, 256, 0, stream>>>(ADF, d1_w, W2);
    k_qkv <<<dim3(1024, 3), 256, 0, stream>>>(x, attn_kernel, QHI, KHI, KLO, VB);
    k_flash_mfma<<<dim3(32, 16), 256, 0, stream>>>(QHI, KHI, KLO, VB, VO);
    k_hpool<<<dim3(64, 16), 256, 0, stream>>>(VO, W2, d1_b, PMAX, PSUM);
    k_pred<<<16, 256, 0, stream>>>(PMAX, PSUM, POOL);
    k_fc1 <<<16, 512, 0, stream>>>(POOL, fc1_w, fc1_b, FC1);
    k_fc2 <<<16, 256, 0, stream>>>(FC1, fc2_w, fc2_b, out);
}

// Round 3
// 327.404 us; speedup vs baseline: 4.5482x; 1.6980x over previous
//
#include <hip/hip_runtime.h>

typedef __attribute__((ext_vector_type(8))) short bf8v;   // 8 bf16 (4 VGPRs)
typedef __attribute__((ext_vector_type(4))) float f4v;    // MFMA accumulator
typedef __attribute__((ext_vector_type(8))) unsigned short us8;
typedef __attribute__((ext_vector_type(4))) unsigned short us4;
typedef unsigned short u16;

__device__ __forceinline__ u16 f2bf(float f) {            // f32 -> bf16 RNE
    unsigned int u = __builtin_bit_cast(unsigned int, f);
    u += 0x7fffu + ((u >> 16) & 1u);
    return (u16)(u >> 16);
}
__device__ __forceinline__ float bf2f(u16 h) {
    return __builtin_bit_cast(float, (unsigned int)h << 16);
}

// ---------------- fold attn_dense: AD_f[h][e] = sum_k ad[k*100+h][e] -------
__global__ void k_fold(const float* __restrict__ ad, float* __restrict__ adf) {
    int i = blockIdx.x * 256 + threadIdx.x;
    if (i < 100 * 400) {
        int h = i / 400, e = i % 400;
        float s = 0.f;
        #pragma unroll
        for (int k = 0; k < 4; ++k) s += ad[(k * 100 + h) * 400 + e];
        adf[i] = s;
    }
}

// ---------------- W2[h][j] = sum_e AD_f[h][e] * d1_w[e][j] -----------------
__global__ void k_w2(const float* __restrict__ adf, const float* __restrict__ d1w,
                     float* __restrict__ w2) {
    int i = blockIdx.x * 256 + threadIdx.x;
    if (i < 100 * 400) {
        int h = i / 400, j = i % 400;
        float acc = 0.f;
        for (int e = 0; e < 400; ++e) acc += adf[h * 400 + e] * d1w[e * 400 + j];
        w2[i] = acc;
    }
}

// ---------------- W prep: split attn_kernel into bf16 hi/lo tiles ----------
// Layout: [3 m][13 ks][2 hl][128 n][32 k] bf16  (n>=100 or gk>=400 zero-pad)
__global__ void k_wprep(const float* __restrict__ ak, u16* __restrict__ wsp) {
    int i = blockIdx.x * 256 + threadIdx.x;          // 3*13*4096 = 159744
    if (i >= 159744) return;
    int k = i & 31, n = (i >> 5) & 127;
    int x = i >> 12;                                  // m*13 + ks
    int ks = x % 13, m = x / 13;
    int gk = ks * 32 + k;
    float v = (n < 100 && gk < 400) ? ak[m * 40000 + gk * 100 + n] : 0.f;
    u16 hb = f2bf(v);
    u16 lb = f2bf(v - bf2f(hb));
    long base = (long)x * 8192;
    wsp[base + n * 32 + k] = hb;
    wsp[base + 4096 + n * 32 + k] = lb;
}

// ---------------- QKV via MFMA: [32768,400(pad416)] x [400,100(pad128)] ----
// grid (512, 3) block 256 (4 waves x 16 rows = 64-row M-tile).
// m=0: Q=(xhi+xlo)*whi -> QHI bf16; m=1: K 3-term -> KHI/KLO split;
// m=2: V=(xhi+xlo)*whi -> VT bf16 TRANSPOSED [b][128 d][2048 q].
__global__ __launch_bounds__(256) void k_gemm_qkv(
    const float* __restrict__ x, const u16* __restrict__ wsp,
    u16* __restrict__ QHI, u16* __restrict__ KHI, u16* __restrict__ KLO,
    u16* __restrict__ VT) {
    __shared__ __align__(16) u16 xsh[64 * 32], xsl[64 * 32];
    __shared__ __align__(16) u16 wsh[128 * 32], wsl[128 * 32];
    __shared__ __align__(16) u16 epi[8192];          // [64][128] or [128][64]

    const int tid = threadIdx.x;
    const int m = blockIdx.y;
    const long row0 = (long)blockIdx.x * 64;
    const int w = tid >> 6, l = tid & 63, g = l >> 4, c15 = l & 15;
    const int sr = tid >> 2, skc = tid & 3;          // x-stage: row, k-chunk

    f4v acc[8];
    #pragma unroll
    for (int nt = 0; nt < 8; ++nt) acc[nt] = (f4v){0.f, 0.f, 0.f, 0.f};

    const u16* wbase = wsp + (long)m * 13 * 8192;

    for (int ks = 0; ks < 13; ++ks) {
        __syncthreads();
        // ---- stage x [64 rows][32 k]: f32 -> bf16 hi/lo
        float va[8];
        if (ks * 32 + skc * 8 < 400) {
            const float* xp = x + (row0 + sr) * 400 + ks * 32 + skc * 8;
            float4 p0 = *(const float4*)xp;
            float4 p1 = *(const float4*)(xp + 4);
            va[0] = p0.x; va[1] = p0.y; va[2] = p0.z; va[3] = p0.w;
            va[4] = p1.x; va[5] = p1.y; va[6] = p1.z; va[7] = p1.w;
        } else {
            #pragma unroll
            for (int j = 0; j < 8; ++j) va[j] = 0.f;
        }
        us8 hi8, lo8;
        #pragma unroll
        for (int j = 0; j < 8; ++j) {
            u16 h = f2bf(va[j]);
            hi8[j] = h;
            lo8[j] = f2bf(va[j] - bf2f(h));
        }
        *(us8*)&xsh[sr * 32 + skc * 8] = hi8;
        *(us8*)&xsl[sr * 32 + skc * 8] = lo8;
        // ---- stage W hi/lo [128 n][32 k] (contiguous copy)
        const u16* wsrc = wbase + (long)ks * 8192;
        #pragma unroll
        for (int r = 0; r < 4; ++r) {
            int u = tid + r * 256;
            u16* dst = (u >> 9) ? wsl : wsh;
            *(us8*)&dst[(u & 511) * 8] = *(const us8*)&wsrc[u * 8];
        }
        __syncthreads();
        // ---- MFMA
        bf8v ah = *(const bf8v*)&xsh[(w * 16 + c15) * 32 + g * 8];
        bf8v al = *(const bf8v*)&xsl[(w * 16 + c15) * 32 + g * 8];
        #pragma unroll
        for (int nt = 0; nt < 8; ++nt) {
            bf8v bh = *(const bf8v*)&wsh[(nt * 16 + c15) * 32 + g * 8];
            acc[nt] = __builtin_amdgcn_mfma_f32_16x16x32_bf16(ah, bh, acc[nt], 0, 0, 0);
            acc[nt] = __builtin_amdgcn_mfma_f32_16x16x32_bf16(al, bh, acc[nt], 0, 0, 0);
            if (m == 1) {
                bf8v bl = *(const bf8v*)&wsl[(nt * 16 + c15) * 32 + g * 8];
                acc[nt] = __builtin_amdgcn_mfma_f32_16x16x32_bf16(ah, bl, acc[nt], 0, 0, 0);
            }
        }
    }

    // ---- epilogue (C-layout: row = 4g+r within wave's 16, col = nt*16+c15)
    if (m == 2) {
        // deposit transposed: epi[128 d][64 q], swizzled
        __syncthreads();
        #pragma unroll
        for (int nt = 0; nt < 8; ++nt) {
            int d = nt * 16 + c15;
            int q0 = w * 16 + 4 * g;
            us4 v4;
            #pragma unroll
            for (int r = 0; r < 4; ++r) v4[r] = f2bf(acc[nt][r]);
            *(us4*)&epi[d * 64 + (q0 ^ ((d & 7) << 3))] = v4;
        }
        __syncthreads();
        const int b = (int)(row0 >> 11);
        const int qg = (int)(row0 & 2047);
        #pragma unroll
        for (int r = 0; r < 4; ++r) {
            int u = tid + r * 256;
            int d = u >> 3, c = u & 7;
            *(us8*)&VT[(long)b * 262144 + (long)d * 2048 + qg + c * 8] =
                *(const us8*)&epi[d * 64 + ((c * 8) ^ ((d & 7) << 3))];
        }
    } else {
        // deposit row-major bf16 (hi), coalesced write; K adds a lo round
        __syncthreads();
        #pragma unroll
        for (int nt = 0; nt < 8; ++nt) {
            #pragma unroll
            for (int r = 0; r < 4; ++r) {
                int row = w * 16 + 4 * g + r, col = nt * 16 + c15;
                epi[row * 128 + (col ^ ((row & 7) << 3))] = f2bf(acc[nt][r]);
            }
        }
        __syncthreads();
        u16* OUT = (m == 0) ? QHI : KHI;
        #pragma unroll
        for (int r = 0; r < 4; ++r) {
            int u = tid + r * 256;
            int row = u >> 4, c = u & 15;
            *(us8*)&OUT[(row0 + row) * 128 + c * 8] =
                *(const us8*)&epi[row * 128 + ((c * 8) ^ ((row & 7) << 3))];
        }
        if (m == 1) {
            __syncthreads();
            #pragma unroll
            for (int nt = 0; nt < 8; ++nt) {
                #pragma unroll
                for (int r = 0; r < 4; ++r) {
                    int row = w * 16 + 4 * g + r, col = nt * 16 + c15;
                    u16 h = f2bf(acc[nt][r]);
                    epi[row * 128 + (col ^ ((row & 7) << 3))] =
                        f2bf(acc[nt][r] - bf2f(h));
                }
            }
            __syncthreads();
            #pragma unroll
            for (int r = 0; r < 4; ++r) {
                int u = tid + r * 256;
                int row = u >> 4, c = u & 15;
                *(us8*)&KLO[(row0 + row) * 128 + c * 8] =
                    *(const us8*)&epi[row * 128 + ((c * 8) ^ ((row & 7) << 3))];
            }
        }
    }
}

// ---------------- MFMA flash attention -------------------------------------
// grid (32, 16), block 256 (4 waves x 16 q-rows). KV tile 64, D padded 128.
// V comes in pre-transposed (VT [b][128 d][2048 k]) -> clean swizzled staging.
__global__ __launch_bounds__(256) void k_flash_mfma(
    const u16* __restrict__ Qg, const u16* __restrict__ Khig,
    const u16* __restrict__ Klog, const u16* __restrict__ VTg,
    float* __restrict__ vo) {
    __shared__ __align__(16) char KhiS[16384];     // [64 keys][128 d] swizzled
    __shared__ __align__(16) char KloS[16384];
    __shared__ __align__(16) char VtS[16384];      // [128 d][64 k] swizzled
    __shared__ __align__(16) char PS[4][2048];     // per-wave P [16 q][64 k]

    const int tid = threadIdx.x;
    const int w = tid >> 6;
    const int l = tid & 63;
    const int c15 = l & 15;
    const int g = l >> 4;
    const int b = blockIdx.y, qt = blockIdx.x;

    const long bbase = (long)b * 2048 * 128;
    const u16* qp = Qg + bbase + (long)(qt * 64 + w * 16 + c15) * 128;

    bf8v qh[4];
    #pragma unroll
    for (int ks = 0; ks < 4; ++ks) qh[ks] = *(const bf8v*)(qp + ks * 32 + g * 8);

    f4v O[7];
    #pragma unroll
    for (int i = 0; i < 7; ++i) O[i] = (f4v){0.f, 0.f, 0.f, 0.f};
    float mrow[4] = {-1e30f, -1e30f, -1e30f, -1e30f};
    float lrow[4] = {0.f, 0.f, 0.f, 0.f};

    const u16* Khb = Khig + bbase;
    const u16* Klb = Klog + bbase;
    const u16* VTb = VTg + bbase;                  // [128 d][2048 k]
    char* Pw = PS[w];

    for (int t = 0; t < 32; ++t) {
        __syncthreads();                            // prev compute done
        // ---- stage Khi/Klo, XOR-swizzled rows (16B chunk c -> c^(row&7))
        #pragma unroll
        for (int r = 0; r < 4; ++r) {
            int u = tid + r * 256;                  // 1024 16B-chunks per array
            int row = u >> 4, c = u & 15;
            long gs = (long)(t * 64 + row) * 128 + c * 8;
            int dst = row * 256 + ((c * 16) ^ ((row & 7) << 4));
            *(bf8v*)(KhiS + dst) = *(const bf8v*)(Khb + gs);
            *(bf8v*)(KloS + dst) = *(const bf8v*)(Klb + gs);
        }
        // ---- stage V^T [128 d][64 k]: straight swizzled chunk copy
        #pragma unroll
        for (int r = 0; r < 4; ++r) {
            int u = tid + r * 256;                  // 1024 chunks
            int d = u >> 3, c = u & 7;
            *(bf8v*)(VtS + d * 128 + ((c * 16) ^ ((d & 7) << 4))) =
                *(const bf8v*)(VTb + (long)d * 2048 + t * 64 + c * 8);
        }
        __syncthreads();

        // ---- QK^T: S[16q x 64k] (C: row=4g+r=q, col=c15=key)
        f4v s[4];
        #pragma unroll
        for (int nt = 0; nt < 4; ++nt) s[nt] = (f4v){0.f, 0.f, 0.f, 0.f};
        #pragma unroll
        for (int ks = 0; ks < 4; ++ks) {
            #pragma unroll
            for (int nt = 0; nt < 4; ++nt) {
                int key = nt * 16 + c15;
                int off = key * 256 + ((ks * 64 + g * 16) ^ ((key & 7) << 4));
                bf8v kh = *(const bf8v*)(KhiS + off);
                bf8v kl = *(const bf8v*)(KloS + off);
                s[nt] = __builtin_amdgcn_mfma_f32_16x16x32_bf16(qh[ks], kh, s[nt], 0, 0, 0);
                s[nt] = __builtin_amdgcn_mfma_f32_16x16x32_bf16(qh[ks], kl, s[nt], 0, 0, 0);
            }
        }

        // ---- online softmax: per C-register r (row q = 4g+r), reduce c15
        float sc[4];
        #pragma unroll
        for (int r = 0; r < 4; ++r) {
            float mx = fmaxf(fmaxf(s[0][r], s[1][r]), fmaxf(s[2][r], s[3][r]));
            mx = fmaxf(mx, __shfl_xor(mx, 1));
            mx = fmaxf(mx, __shfl_xor(mx, 2));
            mx = fmaxf(mx, __shfl_xor(mx, 4));
            mx = fmaxf(mx, __shfl_xor(mx, 8));
            float mnew = fmaxf(mrow[r], mx * 0.1f);
            sc[r] = __expf(mrow[r] - mnew);
            mrow[r] = mnew;
            float sum = 0.f;
            #pragma unroll
            for (int nt = 0; nt < 4; ++nt) {
                float p = __expf(s[nt][r] * 0.1f - mnew);
                s[nt][r] = p;
                sum += p;
            }
            sum += __shfl_xor(sum, 1);
            sum += __shfl_xor(sum, 2);
            sum += __shfl_xor(sum, 4);
            sum += __shfl_xor(sum, 8);
            lrow[r] = lrow[r] * sc[r] + sum;
        }
        // ---- P -> per-wave swizzled LDS (bf16) for PV A-frag re-layout
        #pragma unroll
        for (int nt = 0; nt < 4; ++nt) {
            #pragma unroll
            for (int r = 0; r < 4; ++r) {
                int q = g * 4 + r;
                *(u16*)(Pw + q * 128 + ((nt * 32 + c15 * 2) ^ ((q & 7) << 4))) =
                    f2bf(s[nt][r]);
            }
        }
        // ---- rescale O
        #pragma unroll
        for (int dt = 0; dt < 7; ++dt) {
            #pragma unroll
            for (int r = 0; r < 4; ++r) O[dt][r] *= sc[r];
        }
        // ---- PV: O[16q][112d] += P[16q][64k] * V[64k][d]
        #pragma unroll
        for (int k0 = 0; k0 < 2; ++k0) {
            bf8v pa = *(const bf8v*)(Pw + c15 * 128 +
                                     ((k0 * 64 + g * 16) ^ ((c15 & 7) << 4)));
            #pragma unroll
            for (int dt = 0; dt < 7; ++dt) {
                int d = dt * 16 + c15;
                bf8v vf = *(const bf8v*)(VtS + d * 128 +
                                         ((k0 * 64 + g * 16) ^ ((d & 7) << 4)));
                O[dt] = __builtin_amdgcn_mfma_f32_16x16x32_bf16(pa, vf, O[dt], 0, 0, 0);
            }
        }
    }

    // ---- normalize + store
    const long qbase = (long)b * 2048 + qt * 64 + w * 16 + g * 4;
    #pragma unroll
    for (int r = 0; r < 4; ++r) {
        float inv = 1.f / lrow[r];
        #pragma unroll
        for (int dt = 0; dt < 7; ++dt) {
            int d = dt * 16 + c15;
            if (d < 100) vo[(qbase + r) * 100 + d] = O[dt][r] * inv;
        }
    }
}

// ---------------- h = relu(V@W2 + d1_b); partial max/sum pool --------------
__global__ __launch_bounds__(256) void k_hpool(const float* __restrict__ vo,
                                               const float* __restrict__ w2,
                                               const float* __restrict__ d1b,
                                               float* __restrict__ pmax,
                                               float* __restrict__ psum) {
    __shared__ float Vt[32 * 100];
    __shared__ float red[2][8][128];
    const int tid = threadIdx.x;
    const int b = blockIdx.y, rt = blockIdx.x;
    const float* vb = vo + ((long)b * 2048 + rt * 32) * 100;
    for (int e = tid; e < 3200; e += 256) Vt[e] = vb[e];
    __syncthreads();

    const int tx = tid & 31, ty = tid >> 5;
    for (int pass = 0; pass < 4; ++pass) {
        int jq = pass * 32 + tx;
        bool act = (jq < 100);
        if (act) {
            int j4 = jq * 4;
            float4 bias = *(const float4*)&d1b[j4];
            float acc[4][4];
            #pragma unroll
            for (int i = 0; i < 4; ++i) {
                acc[i][0] = bias.x; acc[i][1] = bias.y;
                acc[i][2] = bias.z; acc[i][3] = bias.w;
            }
            for (int d = 0; d < 100; d += 2) {
                float4 wa = *(const float4*)&w2[d * 400 + j4];
                float4 wb = *(const float4*)&w2[(d + 1) * 400 + j4];
                #pragma unroll
                for (int i = 0; i < 4; ++i) {
                    float2 xv = *(const float2*)&Vt[(ty * 4 + i) * 100 + d];
                    acc[i][0] += xv.x * wa.x + xv.y * wb.x;
                    acc[i][1] += xv.x * wa.y + xv.y * wb.y;
                    acc[i][2] += xv.x * wa.z + xv.y * wb.z;
                    acc[i][3] += xv.x * wa.w + xv.y * wb.w;
                }
            }
            #pragma unroll
            for (int c = 0; c < 4; ++c) {
                float h0 = fmaxf(acc[0][c], 0.f), h1 = fmaxf(acc[1][c], 0.f);
                float h2 = fmaxf(acc[2][c], 0.f), h3 = fmaxf(acc[3][c], 0.f);
                red[0][ty][tx * 4 + c] = fmaxf(fmaxf(h0, h1), fmaxf(h2, h3));
                red[1][ty][tx * 4 + c] = h0 + h1 + h2 + h3;
            }
        }
        __syncthreads();
        if (tid < 128) {
            int jgl = pass * 128 + tid;
            if (jgl < 400) {
                float mx = red[0][0][tid], sm = red[1][0][tid];
                #pragma unroll
                for (int t = 1; t < 8; ++t) {
                    mx = fmaxf(mx, red[0][t][tid]);
                    sm += red[1][t][tid];
                }
                pmax[((long)b * 64 + rt) * 400 + jgl] = mx;
                psum[((long)b * 64 + rt) * 400 + jgl] = sm;
            }
        }
        __syncthreads();
    }
}

// ---------------- reduce partials -> pooled[b][800] ------------------------
__global__ void k_pred(const float* __restrict__ pmax, const float* __restrict__ psum,
                       float* __restrict__ pooled) {
    const int b = blockIdx.x;
    for (int j = threadIdx.x; j < 400; j += 256) {
        float mx = -1e30f, sm = 0.f;
        for (int t = 0; t < 64; ++t) {
            mx = fmaxf(mx, pmax[((long)b * 64 + t) * 400 + j]);
            sm += psum[((long)b * 64 + t) * 400 + j];
        }
        pooled[b * 800 + j] = mx;
        pooled[b * 800 + 400 + j] = sm * (1.f / 2048.f);
    }
}

// ---------------- fc1 / fc2 ------------------------------------------------
__global__ void k_fc1(const float* __restrict__ pooled, const float* __restrict__ w,
                      const float* __restrict__ bias, float* __restrict__ out) {
    const int b = blockIdx.x, j = threadIdx.x;
    float acc = bias[j];
    for (int k = 0; k < 800; ++k) acc += pooled[b * 800 + k] * w[k * 512 + j];
    out[b * 512 + j] = fmaxf(acc, 0.f);
}

__global__ void k_fc2(const float* __restrict__ h, const float* __restrict__ w,
                      const float* __restrict__ bias, float* __restrict__ out) {
    const int b = blockIdx.x, j = threadIdx.x;
    float acc = bias[j];
    for (int k = 0; k < 512; ++k) acc += h[b * 512 + k] * w[k * 256 + j];
    out[b * 256 + j] = fmaxf(acc, 0.f);
}

extern "C" void kernel_launch(void* const* d_in, const int* in_sizes, int n_in,
                              void* d_out, int out_size, void* d_ws, size_t ws_size,
                              hipStream_t stream) {
    const float* x          = (const float*)d_in[0];
    const float* attn_kernel= (const float*)d_in[1];
    const float* attn_dense = (const float*)d_in[2];
    const float* d1_w       = (const float*)d_in[3];
    const float* d1_b       = (const float*)d_in[4];
    const float* fc1_w      = (const float*)d_in[5];
    const float* fc1_b      = (const float*)d_in[6];
    const float* fc2_w      = (const float*)d_in[7];
    const float* fc2_b      = (const float*)d_in[8];
    float* out = (float*)d_out;
    char*  wsb = (char*)d_ws;

    // ws layout (bytes), total ~48.6 MB
    u16*   QHI  = (u16*)(wsb);                    //  8,388,608
    u16*   KHI  = (u16*)(wsb + 8388608);
    u16*   KLO  = (u16*)(wsb + 16777216);
    u16*   VT   = (u16*)(wsb + 25165824);         //  8,388,608 [16][128][2048]
    u16*   WSP  = (u16*)(wsb + 33554432);         //    638,976
    float* VO   = (float*)(wsb + 34193408);       // 13,107,200
    float* ADF  = (float*)(wsb + 47300608);
    float* W2   = (float*)(wsb + 47460608);
    float* PMAX = (float*)(wsb + 47620608);
    float* PSUM = (float*)(wsb + 49259008);
    float* POOL = (float*)(wsb + 50897408);
    float* FC1  = (float*)(wsb + 50948608);

    k_wprep<<<624, 256, 0, stream>>>(attn_kernel, WSP);
    k_fold<<<157, 256, 0, stream>>>(attn_dense, ADF);
    k_w2  <<<157, 256, 0, stream>>>(ADF, d1_w, W2);
    k_gemm_qkv<<<dim3(512, 3), 256, 0, stream>>>(x, WSP, QHI, KHI, KLO, VT);
    k_flash_mfma<<<dim3(32, 16), 256, 0, stream>>>(QHI, KHI, KLO, VT, VO);
    k_hpool<<<dim3(64, 16), 256, 0, stream>>>(VO, W2, d1_b, PMAX, PSUM);
    k_pred<<<16, 256, 0, stream>>>(PMAX, PSUM, POOL);
    k_fc1 <<<16, 512, 0, stream>>>(POOL, fc1_w, fc1_b, FC1);
    k_fc2 <<<16, 256, 0, stream>>>(FC1, fc2_w, fc2_b, out);
}

// Round 4
// 285.287 us; speedup vs baseline: 5.2197x; 1.1476x over previous
//
#include <hip/hip_runtime.h>

typedef __attribute__((ext_vector_type(8))) _Float16 f16x8;
typedef __attribute__((ext_vector_type(2))) _Float16 h2v;
typedef __attribute__((ext_vector_type(4))) float f4v;
typedef __attribute__((ext_vector_type(8))) unsigned short us8;
typedef __attribute__((ext_vector_type(4))) unsigned short us4;
typedef unsigned short u16;

__device__ __forceinline__ u16 h2b(_Float16 h) { return __builtin_bit_cast(u16, h); }

// ---------------- fold attn_dense: AD_f[h][e] = sum_k ad[k*100+h][e] -------
__global__ void k_fold(const float* __restrict__ ad, float* __restrict__ adf) {
    int i = blockIdx.x * 256 + threadIdx.x;
    if (i < 100 * 400) {
        int h = i / 400, e = i % 400;
        float s = 0.f;
        #pragma unroll
        for (int k = 0; k < 4; ++k) s += ad[(k * 100 + h) * 400 + e];
        adf[i] = s;
    }
}

// ---- W2 = ADF @ d1_w, emitted as fp16 MFMA B-fragments [25 nt][4 ks][64][8]
__global__ void k_w2f(const float* __restrict__ adf, const float* __restrict__ d1w,
                      u16* __restrict__ w2f) {
    int i = blockIdx.x * 256 + threadIdx.x;       // 128 d x 400 j
    if (i >= 51200) return;
    int d = i / 400, j = i % 400;
    float acc = 0.f;
    if (d < 100) {
        for (int e = 0; e < 400; ++e) acc += adf[d * 400 + e] * d1w[e * 400 + j];
    }
    int idx = ((j >> 4) * 4 + (d >> 5)) * 512 + (((d >> 3) & 3) * 16 + (j & 15)) * 8 + (d & 7);
    w2f[idx] = h2b((_Float16)acc);
}

// ---- W prep: fp16 hi/lo tiles [3 m][13 ks][2 hl][128 n][32 k], x-swizzled -
__global__ void k_wprep(const float* __restrict__ ak, u16* __restrict__ wsp) {
    int i = blockIdx.x * 256 + threadIdx.x;       // 3*13*4096 = 159744
    if (i >= 159744) return;
    int k = i & 31, n = (i >> 5) & 127;
    int xx = i >> 12;                             // m*13 + ks
    int ks = xx % 13, m = xx / 13;
    int gk = ks * 32 + k;
    float v = (n < 100 && gk < 400) ? ak[m * 40000 + gk * 100 + n] : 0.f;
    _Float16 hb = (_Float16)v;
    _Float16 lb = (_Float16)(v - (float)hb);
    long base = (long)xx * 8192;
    int pos = n * 32 + ((((k >> 3) ^ (n & 3)) << 3) | (k & 7));
    wsp[base + pos] = h2b(hb);
    wsp[base + 4096 + pos] = h2b(lb);
}

// ---------------- QKV via fp16 MFMA ----------------------------------------
// grid 1536 (m = bx%3 adjacent for x L2 reuse), block 256 (4 waves, 64 rows).
// m=0: Q=(xh+xl)wh + xh*wl, scaled 0.1*log2e -> QH row-major [32768][128]
// m=1: K 3-term -> KH pre-swizzled tile image [b][t][64r][16chunk]
// m=2: V 2-term -> VT transposed image [b][t][128d][8chunk]
__global__ __launch_bounds__(256) void k_gemm_qkv(
    const float* __restrict__ x, const u16* __restrict__ wsp,
    u16* __restrict__ QH, u16* __restrict__ KH, u16* __restrict__ VT) {
    __shared__ __align__(16) u16 xsh[2048], xsl[2048];
    __shared__ __align__(16) u16 wsh[4096], wsl[4096];
    __shared__ __align__(16) u16 epi[8192];

    const int tid = threadIdx.x;
    const int bx = blockIdx.x;
    const int m = bx % 3;
    const int rowblk = bx / 3;
    const long row0 = (long)rowblk * 64;
    const int w = tid >> 6, l = tid & 63, g = l >> 4, c15 = l & 15;
    const int sr = tid >> 2, skc = tid & 3;

    f4v acc[8];
    #pragma unroll
    for (int nt = 0; nt < 8; ++nt) acc[nt] = (f4v){0.f, 0.f, 0.f, 0.f};

    const u16* wbase = wsp + (long)m * 13 * 8192;

    for (int ks = 0; ks < 13; ++ks) {
        __syncthreads();
        // stage x rows -> fp16 hi/lo (swizzled: chunk ^ (row&3))
        float va[8];
        if (ks * 32 + skc * 8 < 400) {
            const float* xp = x + (row0 + sr) * 400 + ks * 32 + skc * 8;
            float4 p0 = *(const float4*)xp;
            float4 p1 = *(const float4*)(xp + 4);
            va[0] = p0.x; va[1] = p0.y; va[2] = p0.z; va[3] = p0.w;
            va[4] = p1.x; va[5] = p1.y; va[6] = p1.z; va[7] = p1.w;
        } else {
            #pragma unroll
            for (int j = 0; j < 8; ++j) va[j] = 0.f;
        }
        us8 hi8, lo8;
        #pragma unroll
        for (int j = 0; j < 8; ++j) {
            _Float16 h = (_Float16)va[j];
            hi8[j] = h2b(h);
            lo8[j] = h2b((_Float16)(va[j] - (float)h));
        }
        int xpos = sr * 32 + ((skc * 8) ^ ((sr & 3) << 3));
        *(us8*)&xsh[xpos] = hi8;
        *(us8*)&xsl[xpos] = lo8;
        // stage W hi/lo (straight copy; swizzle baked into WSP)
        const u16* wsrc = wbase + (long)ks * 8192;
        #pragma unroll
        for (int r = 0; r < 4; ++r) {
            int u = tid + r * 256;
            u16* dst = (u >> 9) ? wsl : wsh;
            *(us8*)&dst[(u & 511) * 8] = *(const us8*)&wsrc[(long)u * 8];
        }
        __syncthreads();
        const int arow = w * 16 + c15;
        const int axo = arow * 32 + ((g * 8) ^ ((arow & 3) << 3));
        f16x8 ah = *(const f16x8*)&xsh[axo];
        f16x8 al = *(const f16x8*)&xsl[axo];
        #pragma unroll
        for (int nt = 0; nt < 8; ++nt) {
            int brow = nt * 16 + c15;
            int boff = brow * 32 + ((g * 8) ^ ((brow & 3) << 3));
            f16x8 bh = *(const f16x8*)&wsh[boff];
            acc[nt] = __builtin_amdgcn_mfma_f32_16x16x32_f16(ah, bh, acc[nt], 0, 0, 0);
            acc[nt] = __builtin_amdgcn_mfma_f32_16x16x32_f16(al, bh, acc[nt], 0, 0, 0);
            if (m != 2) {
                f16x8 bl = *(const f16x8*)&wsl[boff];
                acc[nt] = __builtin_amdgcn_mfma_f32_16x16x32_f16(ah, bl, acc[nt], 0, 0, 0);
            }
        }
    }
    __syncthreads();

    if (m == 2) {
        // deposit transposed V image: epi[d][q] with XOR(q ^ 8*(d&7))
        #pragma unroll
        for (int nt = 0; nt < 8; ++nt) {
            int d = nt * 16 + c15;
            int q0 = w * 16 + 4 * g;
            us4 v4;
            #pragma unroll
            for (int r = 0; r < 4; ++r) v4[r] = h2b((_Float16)acc[nt][r]);
            *(us4*)&epi[d * 64 + (q0 ^ ((d & 7) << 3))] = v4;
        }
        __syncthreads();
        u16* dst = VT + (long)rowblk * 8192;    // linear dump = swizzled image
        #pragma unroll
        for (int r = 0; r < 4; ++r) {
            int u = tid + r * 256;
            *(us8*)&dst[(long)u * 8] = *(const us8*)&epi[u * 8];
        }
    } else {
        const float qs = (m == 0) ? 0.14426950408889634f : 1.0f;
        #pragma unroll
        for (int nt = 0; nt < 8; ++nt) {
            #pragma unroll
            for (int r = 0; r < 4; ++r) {
                int row = w * 16 + 4 * g + r, col = nt * 16 + c15;
                epi[row * 128 + (col ^ ((row & 7) << 3))] =
                    h2b((_Float16)(acc[nt][r] * qs));
            }
        }
        __syncthreads();
        if (m == 0) {
            // Q: un-swizzle to plain row-major (flash reads frags directly)
            #pragma unroll
            for (int r = 0; r < 4; ++r) {
                int u = tid + r * 256;
                int row = u >> 4, c = u & 15;
                *(us8*)&QH[(row0 + row) * 128 + c * 8] =
                    *(const us8*)&epi[row * 128 + ((c * 8) ^ ((row & 7) << 3))];
            }
        } else {
            u16* dst = KH + (long)rowblk * 8192; // linear dump = swizzled image
            #pragma unroll
            for (int r = 0; r < 4; ++r) {
                int u = tid + r * 256;
                *(us8*)&dst[(long)u * 8] = *(const us8*)&epi[u * 8];
            }
        }
    }
}

// ---------------- fp16 MFMA flash attention --------------------------------
// grid (32,16), block 256 (4 waves x 16 q). KV tile 64. Swapped QK^T:
// s = mfma(K, Q) -> lane holds S[q=c15][16 keys] => softmax = in-lane + 4 shfl.
__global__ __launch_bounds__(256) void k_flash(
    const u16* __restrict__ Qg, const u16* __restrict__ Kg,
    const u16* __restrict__ Vg, u16* __restrict__ VOI) {
    __shared__ __align__(16) char KS[16384];     // K tile image [64r][16c]
    __shared__ __align__(16) char VS[16384];     // V^T tile image [128d][8c]
    __shared__ __align__(16) char PS[4][2048];   // per-wave P [16q][64k] (+sc/l alias)

    const int tid = threadIdx.x;
    const int w = tid >> 6, l = tid & 63, g = l >> 4, c15 = l & 15;
    const int b = blockIdx.y, qt = blockIdx.x;

    const u16* qp = Qg + ((long)b * 2048 + qt * 64 + w * 16 + c15) * 128;
    f16x8 qh[4];
    #pragma unroll
    for (int ks = 0; ks < 4; ++ks) qh[ks] = *(const f16x8*)(qp + ks * 32 + g * 8);

    f4v O[7];
    #pragma unroll
    for (int i = 0; i < 7; ++i) O[i] = (f4v){0.f, 0.f, 0.f, 0.f};
    float mrow = -1e30f, lrow = 0.f;

    const u16* Kb = Kg + (long)b * 32 * 8192;
    const u16* Vb = Vg + (long)b * 32 * 8192;
    char* Pw = PS[w];

    for (int t = 0; t < 32; ++t) {
        __syncthreads();
        // ---- stage K/V: linear conflict-free 16B copies of global images
        #pragma unroll
        for (int r = 0; r < 4; ++r) {
            int u = tid + r * 256;
            *(us8*)(KS + u * 16) = *(const us8*)(Kb + (long)t * 8192 + (long)u * 8);
        }
        #pragma unroll
        for (int r = 0; r < 4; ++r) {
            int u = tid + r * 256;
            *(us8*)(VS + u * 16) = *(const us8*)(Vb + (long)t * 8192 + (long)u * 8);
        }
        __syncthreads();

        // ---- S^T = K Q^T: lane (g,c15) reg (nt,r) = S[q=c15][key=16nt+4g+r]
        f4v s[4];
        #pragma unroll
        for (int nt = 0; nt < 4; ++nt) s[nt] = (f4v){0.f, 0.f, 0.f, 0.f};
        #pragma unroll
        for (int ks = 0; ks < 4; ++ks) {
            #pragma unroll
            for (int nt = 0; nt < 4; ++nt) {
                int key = nt * 16 + c15;
                f16x8 kf = *(const f16x8*)(KS + key * 256 +
                                           ((ks * 64 + g * 16) ^ ((key & 7) << 4)));
                s[nt] = __builtin_amdgcn_mfma_f32_16x16x32_f16(kf, qh[ks], s[nt], 0, 0, 0);
            }
        }

        // ---- online softmax, q = c15 (replicated over g)
        float mx = s[0][0];
        #pragma unroll
        for (int nt = 0; nt < 4; ++nt) {
            #pragma unroll
            for (int r = 0; r < 4; ++r) mx = fmaxf(mx, s[nt][r]);
        }
        mx = fmaxf(mx, __shfl_xor(mx, 16));
        mx = fmaxf(mx, __shfl_xor(mx, 32));
        if (!__all(mx <= mrow)) {
            float mnew = fmaxf(mrow, mx);
            float sc = exp2f(mrow - mnew);
            mrow = mnew;
            lrow *= sc;
            if (g == 0) ((float*)Pw)[c15] = sc;     // alias into PS (pre-P-write)
            float s0 = ((float*)Pw)[4 * g + 0];
            float s1 = ((float*)Pw)[4 * g + 1];
            float s2 = ((float*)Pw)[4 * g + 2];
            float s3 = ((float*)Pw)[4 * g + 3];
            #pragma unroll
            for (int dt = 0; dt < 7; ++dt) {
                O[dt][0] *= s0; O[dt][1] *= s1; O[dt][2] *= s2; O[dt][3] *= s3;
            }
        }
        float sum = 0.f;
        #pragma unroll
        for (int nt = 0; nt < 4; ++nt) {
            #pragma unroll
            for (int r = 0; r < 4; ++r) {
                float p = exp2f(s[nt][r] - mrow);   // Q pre-scaled by 0.1*log2e
                s[nt][r] = p;
                sum += p;
            }
        }
        sum += __shfl_xor(sum, 16);
        sum += __shfl_xor(sum, 32);
        lrow += sum;

        // ---- P -> per-wave swizzled LDS (fp16 pairs)
        #pragma unroll
        for (int nt = 0; nt < 4; ++nt) {
            #pragma unroll
            for (int rr = 0; rr < 2; ++rr) {
                h2v pr;
                pr[0] = (_Float16)s[nt][2 * rr];
                pr[1] = (_Float16)s[nt][2 * rr + 1];
                *(h2v*)(Pw + c15 * 128 +
                        ((32 * nt + 8 * g + 4 * rr) ^ ((c15 & 7) << 4))) = pr;
            }
        }
        // ---- PV: O[16q][112d] += P[16q][64k] V[64k][d]
        #pragma unroll
        for (int k0 = 0; k0 < 2; ++k0) {
            f16x8 pa = *(const f16x8*)(Pw + c15 * 128 +
                                       ((k0 * 64 + g * 16) ^ ((c15 & 7) << 4)));
            #pragma unroll
            for (int dt = 0; dt < 7; ++dt) {
                int d = dt * 16 + c15;
                f16x8 vf = *(const f16x8*)(VS + d * 128 +
                                           ((k0 * 64 + g * 16) ^ ((d & 7) << 4)));
                O[dt] = __builtin_amdgcn_mfma_f32_16x16x32_f16(pa, vf, O[dt], 0, 0, 0);
            }
        }
    }

    // ---- normalize + store fp16 VO image [b][qt][64r][16chunk]
    if (g == 0) ((float*)Pw)[c15] = lrow;
    float linv[4];
    #pragma unroll
    for (int r = 0; r < 4; ++r) linv[r] = 1.f / ((float*)Pw)[4 * g + r];
    u16* vout = VOI + ((long)b * 32 + qt) * 8192;
    #pragma unroll
    for (int r = 0; r < 4; ++r) {
        int rowl = w * 16 + 4 * g + r;
        int rsw = (4 * g + r) & 7;
        #pragma unroll
        for (int dt = 0; dt < 7; ++dt) {
            int d = dt * 16 + c15;
            int pos = rowl * 128 + ((((d >> 3) ^ rsw) << 3) | (d & 7));
            vout[pos] = h2b((_Float16)(O[dt][r] * linv[r]));
        }
        int dz = 112 + c15;
        vout[rowl * 128 + ((((dz >> 3) ^ rsw) << 3) | (dz & 7))] = 0;
    }
}

// ---------------- h = relu(VO@W2 + d1_b) via MFMA; partial max/sum pool ----
// grid (32, 16), block 256. 64 rows per block (matches flash tile image).
__global__ __launch_bounds__(256) void k_hpool(
    const u16* __restrict__ VOI, const u16* __restrict__ W2F,
    const float* __restrict__ d1b, float* __restrict__ pmax,
    float* __restrict__ psum) {
    __shared__ __align__(16) u16 A[8192];
    __shared__ float redM[4][400], redS[4][400];
    const int tid = threadIdx.x;
    const int w = tid >> 6, l = tid & 63, g = l >> 4, c15 = l & 15;
    const int b = blockIdx.y, rt = blockIdx.x;

    const u16* src = VOI + ((long)b * 32 + rt) * 8192;
    #pragma unroll
    for (int r = 0; r < 4; ++r) {
        int u = tid + r * 256;
        *(us8*)&A[u * 8] = *(const us8*)&src[(long)u * 8];
    }
    __syncthreads();

    const int arow = w * 16 + c15;
    f16x8 af[4];
    #pragma unroll
    for (int ks = 0; ks < 4; ++ks)
        af[ks] = *(const f16x8*)&A[arow * 128 + ((ks * 32 + g * 8) ^ ((arow & 7) << 3))];

    for (int nt = 0; nt < 25; ++nt) {
        f4v acc = (f4v){0.f, 0.f, 0.f, 0.f};
        #pragma unroll
        for (int ks = 0; ks < 4; ++ks) {
            f16x8 bf = *(const f16x8*)&W2F[(nt * 4 + ks) * 512 + l * 8];
            acc = __builtin_amdgcn_mfma_f32_16x16x32_f16(af[ks], bf, acc, 0, 0, 0);
        }
        float bias = d1b[nt * 16 + c15];
        float mx4 = -1e30f, sm4 = 0.f;
        #pragma unroll
        for (int r = 0; r < 4; ++r) {
            float h = fmaxf(acc[r] + bias, 0.f);
            mx4 = fmaxf(mx4, h);
            sm4 += h;
        }
        mx4 = fmaxf(mx4, __shfl_xor(mx4, 16));
        mx4 = fmaxf(mx4, __shfl_xor(mx4, 32));
        sm4 += __shfl_xor(sm4, 16);
        sm4 += __shfl_xor(sm4, 32);
        if (g == 0) {
            redM[w][nt * 16 + c15] = mx4;
            redS[w][nt * 16 + c15] = sm4;
        }
    }
    __syncthreads();
    for (int j = tid; j < 400; j += 256) {
        float mx = fmaxf(fmaxf(redM[0][j], redM[1][j]), fmaxf(redM[2][j], redM[3][j]));
        float sm = redS[0][j] + redS[1][j] + redS[2][j] + redS[3][j];
        pmax[((long)b * 32 + rt) * 400 + j] = mx;
        psum[((long)b * 32 + rt) * 400 + j] = sm;
    }
}

// ---------------- reduce partials -> pooled[b][800] ------------------------
__global__ void k_pred(const float* __restrict__ pmax, const float* __restrict__ psum,
                       float* __restrict__ pooled) {
    const int b = blockIdx.x;
    for (int j = threadIdx.x; j < 400; j += 256) {
        float mx = -1e30f, sm = 0.f;
        for (int t = 0; t < 32; ++t) {
            mx = fmaxf(mx, pmax[((long)b * 32 + t) * 400 + j]);
            sm += psum[((long)b * 32 + t) * 400 + j];
        }
        pooled[b * 800 + j] = mx;
        pooled[b * 800 + 400 + j] = sm * (1.f / 2048.f);
    }
}

// ---------------- fc1 / fc2 ------------------------------------------------
__global__ void k_fc1(const float* __restrict__ pooled, const float* __restrict__ w,
                      const float* __restrict__ bias, float* __restrict__ out) {
    const int b = blockIdx.x, j = threadIdx.x;
    float acc = bias[j];
    for (int k = 0; k < 800; ++k) acc += pooled[b * 800 + k] * w[k * 512 + j];
    out[b * 512 + j] = fmaxf(acc, 0.f);
}

__global__ void k_fc2(const float* __restrict__ h, const float* __restrict__ w,
                      const float* __restrict__ bias, float* __restrict__ out) {
    const int b = blockIdx.x, j = threadIdx.x;
    float acc = bias[j];
    for (int k = 0; k < 512; ++k) acc += h[b * 512 + k] * w[k * 256 + j];
    out[b * 256 + j] = fmaxf(acc, 0.f);
}

extern "C" void kernel_launch(void* const* d_in, const int* in_sizes, int n_in,
                              void* d_out, int out_size, void* d_ws, size_t ws_size,
                              hipStream_t stream) {
    const float* x          = (const float*)d_in[0];
    const float* attn_kernel= (const float*)d_in[1];
    const float* attn_dense = (const float*)d_in[2];
    const float* d1_w       = (const float*)d_in[3];
    const float* d1_b       = (const float*)d_in[4];
    const float* fc1_w      = (const float*)d_in[5];
    const float* fc1_b      = (const float*)d_in[6];
    const float* fc2_w      = (const float*)d_in[7];
    const float* fc2_b      = (const float*)d_in[8];
    float* out = (float*)d_out;
    char*  wsb = (char*)d_ws;

    // ws layout (bytes), total ~36.2 MB
    u16*   QH   = (u16*)(wsb);                    // 8,388,608
    u16*   KH   = (u16*)(wsb + 8388608);          // 8,388,608 (tile images)
    u16*   VT   = (u16*)(wsb + 16777216);         // 8,388,608 (tile images)
    u16*   VOI  = (u16*)(wsb + 25165824);         // 8,388,608 (tile images)
    u16*   WSP  = (u16*)(wsb + 33554432);         //   638,976
    u16*   W2F  = (u16*)(wsb + 34193408);         //   102,400
    float* ADF  = (float*)(wsb + 34295808);       //   160,000
    float* PMAX = (float*)(wsb + 34455808);       //   819,200
    float* PSUM = (float*)(wsb + 35275008);       //   819,200
    float* POOL = (float*)(wsb + 36094208);       //    51,200
    float* FC1  = (float*)(wsb + 36145408);       //    32,768

    k_wprep<<<624, 256, 0, stream>>>(attn_kernel, WSP);
    k_fold<<<157, 256, 0, stream>>>(attn_dense, ADF);
    k_w2f <<<200, 256, 0, stream>>>(ADF, d1_w, W2F);
    k_gemm_qkv<<<1536, 256, 0, stream>>>(x, WSP, QH, KH, VT);
    k_flash<<<dim3(32, 16), 256, 0, stream>>>(QH, KH, VT, VOI);
    k_hpool<<<dim3(32, 16), 256, 0, stream>>>(VOI, W2F, d1_b, PMAX, PSUM);
    k_pred<<<16, 256, 0, stream>>>(PMAX, PSUM, POOL);
    k_fc1 <<<16, 512, 0, stream>>>(POOL, fc1_w, fc1_b, FC1);
    k_fc2 <<<16, 256, 0, stream>>>(FC1, fc2_w, fc2_b, out);
}

// Round 5
// 284.768 us; speedup vs baseline: 5.2292x; 1.0018x over previous
//
#include <hip/hip_runtime.h>

typedef __attribute__((ext_vector_type(8))) _Float16 f16x8;
typedef __attribute__((ext_vector_type(2))) _Float16 h2v;
typedef __attribute__((ext_vector_type(4))) float f4v;
typedef __attribute__((ext_vector_type(8))) unsigned short us8;
typedef __attribute__((ext_vector_type(4))) unsigned short us4;
typedef unsigned short u16;

__device__ __forceinline__ u16 h2b(_Float16 h) { return __builtin_bit_cast(u16, h); }
__device__ __forceinline__ float b2f(u16 b) {
    return (float)__builtin_bit_cast(_Float16, b);
}

// ---------------- fold attn_dense: AD_f[h][e] = sum_k ad[k*100+h][e] -------
__global__ void k_fold(const float* __restrict__ ad, float* __restrict__ adf) {
    int i = blockIdx.x * 256 + threadIdx.x;
    if (i < 100 * 400) {
        int h = i / 400, e = i % 400;
        float s = 0.f;
        #pragma unroll
        for (int k = 0; k < 4; ++k) s += ad[(k * 100 + h) * 400 + e];
        adf[i] = s;
    }
}

// ---- W2 = ADF @ d1_w, emitted as fp16 MFMA B-fragments [25 nt][4 ks][64][8]
__global__ void k_w2f(const float* __restrict__ adf, const float* __restrict__ d1w,
                      u16* __restrict__ w2f) {
    int i = blockIdx.x * 256 + threadIdx.x;       // 128 d x 400 j
    if (i >= 51200) return;
    int d = i / 400, j = i % 400;
    float acc = 0.f;
    if (d < 100) {
        for (int e = 0; e < 400; ++e) acc += adf[d * 400 + e] * d1w[e * 400 + j];
    }
    int idx = ((j >> 4) * 4 + (d >> 5)) * 512 + (((d >> 3) & 3) * 16 + (j & 15)) * 8 + (d & 7);
    w2f[idx] = h2b((_Float16)acc);
}

// ---- W prep: fp16 hi/lo tiles [3 m][13 ks][2 hl][128 n][32 k], x-swizzled -
__global__ void k_wprep(const float* __restrict__ ak, u16* __restrict__ wsp) {
    int i = blockIdx.x * 256 + threadIdx.x;       // 3*13*4096 = 159744
    if (i >= 159744) return;
    int k = i & 31, n = (i >> 5) & 127;
    int xx = i >> 12;                             // m*13 + ks
    int ks = xx % 13, m = xx / 13;
    int gk = ks * 32 + k;
    float v = (n < 100 && gk < 400) ? ak[m * 40000 + gk * 100 + n] : 0.f;
    _Float16 hb = (_Float16)v;
    _Float16 lb = (_Float16)(v - (float)hb);
    long base = (long)xx * 8192;
    int pos = n * 32 + ((((k >> 3) ^ (n & 3)) << 3) | (k & 7));
    wsp[base + pos] = h2b(hb);
    wsp[base + 4096 + pos] = h2b(lb);
}

// ---------------- QKV via fp16 MFMA ----------------------------------------
// grid 1536 (m = bx%3 adjacent for x L2 reuse), block 256 (4 waves, 64 rows).
// m=0: Q=(xh+xl)wh + xh*wl, scaled 0.1*log2e -> QH row-major [32768][128]
// m=1: K 3-term -> KH pre-swizzled tile image [b][t][64r][16chunk]
// m=2: V 2-term -> VT transposed image [b][t][128d][8chunk]
__global__ __launch_bounds__(256) void k_gemm_qkv(
    const float* __restrict__ x, const u16* __restrict__ wsp,
    u16* __restrict__ QH, u16* __restrict__ KH, u16* __restrict__ VT) {
    __shared__ __align__(16) u16 xsh[2048], xsl[2048];
    __shared__ __align__(16) u16 wsh[4096], wsl[4096];
    __shared__ __align__(16) u16 epi[8192];

    const int tid = threadIdx.x;
    const int bx = blockIdx.x;
    const int m = bx % 3;
    const int rowblk = bx / 3;
    const long row0 = (long)rowblk * 64;
    const int w = tid >> 6, l = tid & 63, g = l >> 4, c15 = l & 15;
    const int sr = tid >> 2, skc = tid & 3;

    f4v acc[8];
    #pragma unroll
    for (int nt = 0; nt < 8; ++nt) acc[nt] = (f4v){0.f, 0.f, 0.f, 0.f};

    const u16* wbase = wsp + (long)m * 13 * 8192;

    for (int ks = 0; ks < 13; ++ks) {
        __syncthreads();
        // stage x rows -> fp16 hi/lo (swizzled: chunk ^ (row&3))
        float va[8];
        if (ks * 32 + skc * 8 < 400) {
            const float* xp = x + (row0 + sr) * 400 + ks * 32 + skc * 8;
            float4 p0 = *(const float4*)xp;
            float4 p1 = *(const float4*)(xp + 4);
            va[0] = p0.x; va[1] = p0.y; va[2] = p0.z; va[3] = p0.w;
            va[4] = p1.x; va[5] = p1.y; va[6] = p1.z; va[7] = p1.w;
        } else {
            #pragma unroll
            for (int j = 0; j < 8; ++j) va[j] = 0.f;
        }
        us8 hi8, lo8;
        #pragma unroll
        for (int j = 0; j < 8; ++j) {
            _Float16 h = (_Float16)va[j];
            hi8[j] = h2b(h);
            lo8[j] = h2b((_Float16)(va[j] - (float)h));
        }
        int xpos = sr * 32 + ((skc * 8) ^ ((sr & 3) << 3));
        *(us8*)&xsh[xpos] = hi8;
        *(us8*)&xsl[xpos] = lo8;
        // stage W hi/lo (straight copy; swizzle baked into WSP)
        const u16* wsrc = wbase + (long)ks * 8192;
        #pragma unroll
        for (int r = 0; r < 4; ++r) {
            int u = tid + r * 256;
            u16* dst = (u >> 9) ? wsl : wsh;
            *(us8*)&dst[(u & 511) * 8] = *(const us8*)&wsrc[(long)u * 8];
        }
        __syncthreads();
        const int arow = w * 16 + c15;
        const int axo = arow * 32 + ((g * 8) ^ ((arow & 3) << 3));
        f16x8 ah = *(const f16x8*)&xsh[axo];
        f16x8 al = *(const f16x8*)&xsl[axo];
        #pragma unroll
        for (int nt = 0; nt < 8; ++nt) {
            int brow = nt * 16 + c15;
            int boff = brow * 32 + ((g * 8) ^ ((brow & 3) << 3));
            f16x8 bh = *(const f16x8*)&wsh[boff];
            acc[nt] = __builtin_amdgcn_mfma_f32_16x16x32_f16(ah, bh, acc[nt], 0, 0, 0);
            acc[nt] = __builtin_amdgcn_mfma_f32_16x16x32_f16(al, bh, acc[nt], 0, 0, 0);
            if (m != 2) {
                f16x8 bl = *(const f16x8*)&wsl[boff];
                acc[nt] = __builtin_amdgcn_mfma_f32_16x16x32_f16(ah, bl, acc[nt], 0, 0, 0);
            }
        }
    }
    __syncthreads();

    if (m == 2) {
        // deposit transposed V image: epi[d][q] with XOR(q ^ 8*(d&7))
        #pragma unroll
        for (int nt = 0; nt < 8; ++nt) {
            int d = nt * 16 + c15;
            int q0 = w * 16 + 4 * g;
            us4 v4;
            #pragma unroll
            for (int r = 0; r < 4; ++r) v4[r] = h2b((_Float16)acc[nt][r]);
            *(us4*)&epi[d * 64 + (q0 ^ ((d & 7) << 3))] = v4;
        }
        __syncthreads();
        u16* dst = VT + (long)rowblk * 8192;    // linear dump = swizzled image
        #pragma unroll
        for (int r = 0; r < 4; ++r) {
            int u = tid + r * 256;
            *(us8*)&dst[(long)u * 8] = *(const us8*)&epi[u * 8];
        }
    } else {
        const float qs = (m == 0) ? 0.14426950408889634f : 1.0f;
        #pragma unroll
        for (int nt = 0; nt < 8; ++nt) {
            #pragma unroll
            for (int r = 0; r < 4; ++r) {
                int row = w * 16 + 4 * g + r, col = nt * 16 + c15;
                epi[row * 128 + (col ^ ((row & 7) << 3))] =
                    h2b((_Float16)(acc[nt][r] * qs));
            }
        }
        __syncthreads();
        if (m == 0) {
            // Q: un-swizzle to plain row-major (flash reads frags directly)
            #pragma unroll
            for (int r = 0; r < 4; ++r) {
                int u = tid + r * 256;
                int row = u >> 4, c = u & 15;
                *(us8*)&QH[(row0 + row) * 128 + c * 8] =
                    *(const us8*)&epi[row * 128 + ((c * 8) ^ ((row & 7) << 3))];
            }
        } else {
            u16* dst = KH + (long)rowblk * 8192; // linear dump = swizzled image
            #pragma unroll
            for (int r = 0; r < 4; ++r) {
                int u = tid + r * 256;
                *(us8*)&dst[(long)u * 8] = *(const us8*)&epi[u * 8];
            }
        }
    }
}

// ---------------- fp16 MFMA flash attention, KV-split x2 -------------------
// grid (32, 16, 2), block 256 (4 waves x 16 q). Each z-half does 16 KV tiles,
// writes l-normalized fp16 partial-O image + (m,l) per q-row.
__global__ __launch_bounds__(256) void k_flash(
    const u16* __restrict__ Qg, const u16* __restrict__ Kg,
    const u16* __restrict__ Vg, u16* __restrict__ VOI,
    float2* __restrict__ ML) {
    __shared__ __align__(16) char KS[16384];     // K tile image [64r][16c]
    __shared__ __align__(16) char VS[16384];     // V^T tile image [128d][8c]
    __shared__ __align__(16) char PS[4][2048];   // per-wave P [16q][64k] (+sc/l alias)

    const int tid = threadIdx.x;
    const int w = tid >> 6, l = tid & 63, g = l >> 4, c15 = l & 15;
    const int b = blockIdx.y, qt = blockIdx.x, half = blockIdx.z;
    const int t0 = half * 16;

    const u16* qp = Qg + ((long)b * 2048 + qt * 64 + w * 16 + c15) * 128;
    f16x8 qh[4];
    #pragma unroll
    for (int ks = 0; ks < 4; ++ks) qh[ks] = *(const f16x8*)(qp + ks * 32 + g * 8);

    f4v O[7];
    #pragma unroll
    for (int i = 0; i < 7; ++i) O[i] = (f4v){0.f, 0.f, 0.f, 0.f};
    float mrow = -1e30f, lrow = 0.f;

    const u16* Kb = Kg + (long)b * 32 * 8192;
    const u16* Vb = Vg + (long)b * 32 * 8192;
    char* Pw = PS[w];

    for (int t = t0; t < t0 + 16; ++t) {
        __syncthreads();
        // ---- stage K/V: linear conflict-free 16B copies of global images
        #pragma unroll
        for (int r = 0; r < 4; ++r) {
            int u = tid + r * 256;
            *(us8*)(KS + u * 16) = *(const us8*)(Kb + (long)t * 8192 + (long)u * 8);
        }
        #pragma unroll
        for (int r = 0; r < 4; ++r) {
            int u = tid + r * 256;
            *(us8*)(VS + u * 16) = *(const us8*)(Vb + (long)t * 8192 + (long)u * 8);
        }
        __syncthreads();

        // ---- S^T = K Q^T: lane (g,c15) reg (nt,r) = S[q=c15][key=16nt+4g+r]
        f4v s[4];
        #pragma unroll
        for (int nt = 0; nt < 4; ++nt) s[nt] = (f4v){0.f, 0.f, 0.f, 0.f};
        #pragma unroll
        for (int ks = 0; ks < 4; ++ks) {
            #pragma unroll
            for (int nt = 0; nt < 4; ++nt) {
                int key = nt * 16 + c15;
                f16x8 kf = *(const f16x8*)(KS + key * 256 +
                                           ((ks * 64 + g * 16) ^ ((key & 7) << 4)));
                s[nt] = __builtin_amdgcn_mfma_f32_16x16x32_f16(kf, qh[ks], s[nt], 0, 0, 0);
            }
        }

        // ---- online softmax, q = c15 (replicated over g)
        float mx = s[0][0];
        #pragma unroll
        for (int nt = 0; nt < 4; ++nt) {
            #pragma unroll
            for (int r = 0; r < 4; ++r) mx = fmaxf(mx, s[nt][r]);
        }
        mx = fmaxf(mx, __shfl_xor(mx, 16));
        mx = fmaxf(mx, __shfl_xor(mx, 32));
        if (!__all(mx <= mrow)) {
            float mnew = fmaxf(mrow, mx);
            float sc = exp2f(mrow - mnew);
            mrow = mnew;
            lrow *= sc;
            if (g == 0) ((float*)Pw)[c15] = sc;     // alias into PS (pre-P-write)
            float s0 = ((float*)Pw)[4 * g + 0];
            float s1 = ((float*)Pw)[4 * g + 1];
            float s2 = ((float*)Pw)[4 * g + 2];
            float s3 = ((float*)Pw)[4 * g + 3];
            #pragma unroll
            for (int dt = 0; dt < 7; ++dt) {
                O[dt][0] *= s0; O[dt][1] *= s1; O[dt][2] *= s2; O[dt][3] *= s3;
            }
        }
        float sum = 0.f;
        #pragma unroll
        for (int nt = 0; nt < 4; ++nt) {
            #pragma unroll
            for (int r = 0; r < 4; ++r) {
                float p = exp2f(s[nt][r] - mrow);   // Q pre-scaled by 0.1*log2e
                s[nt][r] = p;
                sum += p;
            }
        }
        sum += __shfl_xor(sum, 16);
        sum += __shfl_xor(sum, 32);
        lrow += sum;

        // ---- P -> per-wave swizzled LDS (fp16 pairs)
        #pragma unroll
        for (int nt = 0; nt < 4; ++nt) {
            #pragma unroll
            for (int rr = 0; rr < 2; ++rr) {
                h2v pr;
                pr[0] = (_Float16)s[nt][2 * rr];
                pr[1] = (_Float16)s[nt][2 * rr + 1];
                *(h2v*)(Pw + c15 * 128 +
                        ((32 * nt + 8 * g + 4 * rr) ^ ((c15 & 7) << 4))) = pr;
            }
        }
        // ---- PV: O[16q][112d] += P[16q][64k] V[64k][d]
        #pragma unroll
        for (int k0 = 0; k0 < 2; ++k0) {
            f16x8 pa = *(const f16x8*)(Pw + c15 * 128 +
                                       ((k0 * 64 + g * 16) ^ ((c15 & 7) << 4)));
            #pragma unroll
            for (int dt = 0; dt < 7; ++dt) {
                int d = dt * 16 + c15;
                f16x8 vf = *(const f16x8*)(VS + d * 128 +
                                           ((k0 * 64 + g * 16) ^ ((d & 7) << 4)));
                O[dt] = __builtin_amdgcn_mfma_f32_16x16x32_f16(pa, vf, O[dt], 0, 0, 0);
            }
        }
    }

    // ---- l-normalize + store fp16 partial image [half][b][qt][64r][16chunk]
    if (g == 0) {
        ((float*)Pw)[c15] = lrow;
        ML[half * 32768 + b * 2048 + qt * 64 + w * 16 + c15] =
            make_float2(mrow, lrow);
    }
    float linv[4];
    #pragma unroll
    for (int r = 0; r < 4; ++r) linv[r] = 1.f / ((float*)Pw)[4 * g + r];
    u16* vout = VOI + (long)half * 4194304 + ((long)b * 32 + qt) * 8192;
    #pragma unroll
    for (int r = 0; r < 4; ++r) {
        int rowl = w * 16 + 4 * g + r;
        int rsw = (4 * g + r) & 7;
        #pragma unroll
        for (int dt = 0; dt < 7; ++dt) {
            int d = dt * 16 + c15;
            int pos = rowl * 128 + ((((d >> 3) ^ rsw) << 3) | (d & 7));
            vout[pos] = h2b((_Float16)(O[dt][r] * linv[r]));
        }
        int dz = 112 + c15;
        vout[rowl * 128 + ((((dz >> 3) ^ rsw) << 3) | (dz & 7))] = 0;
    }
}

// ---------------- h = relu(VO@W2 + d1_b) via MFMA; fused half-combine ------
// grid (32, 16), block 256. 64 rows per block (matches flash tile image).
__global__ __launch_bounds__(256) void k_hpool(
    const u16* __restrict__ VOI, const float2* __restrict__ ML,
    const u16* __restrict__ W2F, const float* __restrict__ d1b,
    float* __restrict__ pmax, float* __restrict__ psum) {
    __shared__ __align__(16) u16 A[8192];
    __shared__ float redM[4][400], redS[4][400];
    __shared__ float wgt[64][2];
    const int tid = threadIdx.x;
    const int w = tid >> 6, l = tid & 63, g = l >> 4, c15 = l & 15;
    const int b = blockIdx.y, rt = blockIdx.x;

    // per-row combine weights from (m,l) of the two KV halves
    if (tid < 64) {
        float2 a = ML[b * 2048 + rt * 64 + tid];
        float2 c = ML[32768 + b * 2048 + rt * 64 + tid];
        float m = fmaxf(a.x, c.x);
        float w1 = exp2f(a.x - m) * a.y;
        float w2 = exp2f(c.x - m) * c.y;
        float inv = 1.f / (w1 + w2);
        wgt[tid][0] = w1 * inv;
        wgt[tid][1] = w2 * inv;
    }
    __syncthreads();

    const u16* s1 = VOI + ((long)b * 32 + rt) * 8192;
    const u16* s2 = s1 + 4194304;
    #pragma unroll
    for (int r = 0; r < 4; ++r) {
        int u = tid + r * 256;
        int row = u >> 4;
        us8 p1 = *(const us8*)&s1[(long)u * 8];
        us8 p2 = *(const us8*)&s2[(long)u * 8];
        float w1 = wgt[row][0], w2 = wgt[row][1];
        us8 o;
        #pragma unroll
        for (int j = 0; j < 8; ++j)
            o[j] = h2b((_Float16)(w1 * b2f(p1[j]) + w2 * b2f(p2[j])));
        *(us8*)&A[u * 8] = o;
    }
    __syncthreads();

    const int arow = w * 16 + c15;
    f16x8 af[4];
    #pragma unroll
    for (int ks = 0; ks < 4; ++ks)
        af[ks] = *(const f16x8*)&A[arow * 128 + ((ks * 32 + g * 8) ^ ((arow & 7) << 3))];

    for (int nt = 0; nt < 25; ++nt) {
        f4v acc = (f4v){0.f, 0.f, 0.f, 0.f};
        #pragma unroll
        for (int ks = 0; ks < 4; ++ks) {
            f16x8 bf = *(const f16x8*)&W2F[(nt * 4 + ks) * 512 + l * 8];
            acc = __builtin_amdgcn_mfma_f32_16x16x32_f16(af[ks], bf, acc, 0, 0, 0);
        }
        float bias = d1b[nt * 16 + c15];
        float mx4 = -1e30f, sm4 = 0.f;
        #pragma unroll
        for (int r = 0; r < 4; ++r) {
            float h = fmaxf(acc[r] + bias, 0.f);
            mx4 = fmaxf(mx4, h);
            sm4 += h;
        }
        mx4 = fmaxf(mx4, __shfl_xor(mx4, 16));
        mx4 = fmaxf(mx4, __shfl_xor(mx4, 32));
        sm4 += __shfl_xor(sm4, 16);
        sm4 += __shfl_xor(sm4, 32);
        if (g == 0) {
            redM[w][nt * 16 + c15] = mx4;
            redS[w][nt * 16 + c15] = sm4;
        }
    }
    __syncthreads();
    for (int j = tid; j < 400; j += 256) {
        float mx = fmaxf(fmaxf(redM[0][j], redM[1][j]), fmaxf(redM[2][j], redM[3][j]));
        float sm = redS[0][j] + redS[1][j] + redS[2][j] + redS[3][j];
        pmax[((long)b * 32 + rt) * 400 + j] = mx;
        psum[((long)b * 32 + rt) * 400 + j] = sm;
    }
}

// ---------------- reduce partials -> pooled[b][800] ------------------------
__global__ void k_pred(const float* __restrict__ pmax, const float* __restrict__ psum,
                       float* __restrict__ pooled) {
    const int b = blockIdx.x;
    for (int j = threadIdx.x; j < 400; j += 256) {
        float mx = -1e30f, sm = 0.f;
        for (int t = 0; t < 32; ++t) {
            mx = fmaxf(mx, pmax[((long)b * 32 + t) * 400 + j]);
            sm += psum[((long)b * 32 + t) * 400 + j];
        }
        pooled[b * 800 + j] = mx;
        pooled[b * 800 + 400 + j] = sm * (1.f / 2048.f);
    }
}

// ---------------- fc1 / fc2 ------------------------------------------------
__global__ void k_fc1(const float* __restrict__ pooled, const float* __restrict__ w,
                      const float* __restrict__ bias, float* __restrict__ out) {
    const int b = blockIdx.x, j = threadIdx.x;
    float acc = bias[j];
    for (int k = 0; k < 800; ++k) acc += pooled[b * 800 + k] * w[k * 512 + j];
    out[b * 512 + j] = fmaxf(acc, 0.f);
}

__global__ void k_fc2(const float* __restrict__ h, const float* __restrict__ w,
                      const float* __restrict__ bias, float* __restrict__ out) {
    const int b = blockIdx.x, j = threadIdx.x;
    float acc = bias[j];
    for (int k = 0; k < 512; ++k) acc += h[b * 512 + k] * w[k * 256 + j];
    out[b * 256 + j] = fmaxf(acc, 0.f);
}

extern "C" void kernel_launch(void* const* d_in, const int* in_sizes, int n_in,
                              void* d_out, int out_size, void* d_ws, size_t ws_size,
                              hipStream_t stream) {
    const float* x          = (const float*)d_in[0];
    const float* attn_kernel= (const float*)d_in[1];
    const float* attn_dense = (const float*)d_in[2];
    const float* d1_w       = (const float*)d_in[3];
    const float* d1_b       = (const float*)d_in[4];
    const float* fc1_w      = (const float*)d_in[5];
    const float* fc1_b      = (const float*)d_in[6];
    const float* fc2_w      = (const float*)d_in[7];
    const float* fc2_b      = (const float*)d_in[8];
    float* out = (float*)d_out;
    char*  wsb = (char*)d_ws;

    // ws layout (bytes), total ~44.9 MB
    u16*    QH   = (u16*)(wsb);                    //  8,388,608
    u16*    KH   = (u16*)(wsb + 8388608);          //  8,388,608 (tile images)
    u16*    VT   = (u16*)(wsb + 16777216);         //  8,388,608 (tile images)
    u16*    VOI  = (u16*)(wsb + 25165824);         // 16,777,216 (2 half-images)
    u16*    WSP  = (u16*)(wsb + 41943040);         //    638,976
    u16*    W2F  = (u16*)(wsb + 42582016);         //    102,400
    float*  ADF  = (float*)(wsb + 42684416);       //    160,000
    float*  PMAX = (float*)(wsb + 42844416);       //    819,200
    float*  PSUM = (float*)(wsb + 43663616);       //    819,200
    float*  POOL = (float*)(wsb + 44482816);       //     51,200
    float*  FC1  = (float*)(wsb + 44534016);       //     32,768
    float2* ML   = (float2*)(wsb + 44566784);      //    524,288

    k_wprep<<<624, 256, 0, stream>>>(attn_kernel, WSP);
    k_fold<<<157, 256, 0, stream>>>(attn_dense, ADF);
    k_w2f <<<200, 256, 0, stream>>>(ADF, d1_w, W2F);
    k_gemm_qkv<<<1536, 256, 0, stream>>>(x, WSP, QH, KH, VT);
    k_flash<<<dim3(32, 16, 2), 256, 0, stream>>>(QH, KH, VT, VOI, ML);
    k_hpool<<<dim3(32, 16), 256, 0, stream>>>(VOI, ML, W2F, d1_b, PMAX, PSUM);
    k_pred<<<16, 256, 0, stream>>>(PMAX, PSUM, POOL);
    k_fc1 <<<16, 512, 0, stream>>>(POOL, fc1_w, fc1_b, FC1);
    k_fc2 <<<16, 256, 0, stream>>>(FC1, fc2_w, fc2_b, out);
}

// Round 6
// 231.435 us; speedup vs baseline: 6.4342x; 1.2304x over previous
//
#include <hip/hip_runtime.h>

typedef __attribute__((ext_vector_type(8))) _Float16 f16x8;
typedef __attribute__((ext_vector_type(4))) float f4v;
typedef __attribute__((ext_vector_type(8))) unsigned short us8;
typedef __attribute__((ext_vector_type(4))) unsigned short us4;
typedef unsigned short u16;

__device__ __forceinline__ u16 h2b(_Float16 h) { return __builtin_bit_cast(u16, h); }
__device__ __forceinline__ float b2f(u16 b) {
    return (float)__builtin_bit_cast(_Float16, b);
}

// Raw barrier: drain LDS ops only; leave prefetch global loads in flight.
#define BAR() do { asm volatile("s_waitcnt lgkmcnt(0)" ::: "memory"); \
                   __builtin_amdgcn_s_barrier(); } while (0)

// ---------------- fold attn_dense: AD_f[h][e] = sum_k ad[k*100+h][e] -------
__global__ void k_fold(const float* __restrict__ ad, float* __restrict__ adf) {
    int i = blockIdx.x * 256 + threadIdx.x;
    if (i < 100 * 400) {
        int h = i / 400, e = i % 400;
        float s = 0.f;
        #pragma unroll
        for (int k = 0; k < 4; ++k) s += ad[(k * 100 + h) * 400 + e];
        adf[i] = s;
    }
}

// ---- W2 = ADF @ d1_w, emitted as fp16 MFMA B-fragments [25 nt][4 ks][64][8]
__global__ void k_w2f(const float* __restrict__ adf, const float* __restrict__ d1w,
                      u16* __restrict__ w2f) {
    int i = blockIdx.x * 256 + threadIdx.x;       // 128 d x 400 j
    if (i >= 51200) return;
    int d = i / 400, j = i % 400;
    float acc = 0.f;
    if (d < 100) {
        for (int e = 0; e < 400; ++e) acc += adf[d * 400 + e] * d1w[e * 400 + j];
    }
    int idx = ((j >> 4) * 4 + (d >> 5)) * 512 + (((d >> 3) & 3) * 16 + (j & 15)) * 8 + (d & 7);
    w2f[idx] = h2b((_Float16)acc);
}

// ---- W prep: fp16 hi/lo tiles [3 m][13 ks][2 hl][128 n][32 k], x-swizzled -
__global__ void k_wprep(const float* __restrict__ ak, u16* __restrict__ wsp) {
    int i = blockIdx.x * 256 + threadIdx.x;       // 3*13*4096 = 159744
    if (i >= 159744) return;
    int k = i & 31, n = (i >> 5) & 127;
    int xx = i >> 12;                             // m*13 + ks
    int ks = xx % 13, m = xx / 13;
    int gk = ks * 32 + k;
    float v = (n < 100 && gk < 400) ? ak[m * 40000 + gk * 100 + n] : 0.f;
    _Float16 hb = (_Float16)v;
    _Float16 lb = (_Float16)(v - (float)hb);
    long base = (long)xx * 8192;
    int pos = n * 32 + ((((k >> 3) ^ (n & 3)) << 3) | (k & 7));
    wsp[base + pos] = h2b(hb);
    wsp[base + 4096 + pos] = h2b(lb);
}

// ---------------- QKV via fp16 MFMA, register-prefetch pipelined -----------
// grid 1536 (m = bx%3), block 256 (4 waves, 64 rows).
__global__ __launch_bounds__(256) void k_gemm_qkv(
    const float* __restrict__ x, const u16* __restrict__ wsp,
    u16* __restrict__ QH, u16* __restrict__ KH, u16* __restrict__ VT) {
    __shared__ __align__(16) u16 xsh[2048], xsl[2048];
    __shared__ __align__(16) u16 wsh[4096], wsl[4096];
    __shared__ __align__(16) u16 epi[8192];

    const int tid = threadIdx.x;
    const int bx = blockIdx.x;
    const int m = bx % 3;
    const int rowblk = bx / 3;
    const long row0 = (long)rowblk * 64;
    const int w = tid >> 6, l = tid & 63, g = l >> 4, c15 = l & 15;
    const int sr = tid >> 2, skc = tid & 3;

    f4v acc[8];
    #pragma unroll
    for (int nt = 0; nt < 8; ++nt) acc[nt] = (f4v){0.f, 0.f, 0.f, 0.f};

    const u16* wbase = wsp + (long)m * 13 * 8192;

    float4 xr0, xr1;
    us8 wr[4];
    {   // prologue loads ks=0
        const float* xp = x + (row0 + sr) * 400 + skc * 8;
        xr0 = *(const float4*)xp;
        xr1 = *(const float4*)(xp + 4);
        #pragma unroll
        for (int r = 0; r < 4; ++r)
            wr[r] = *(const us8*)&wbase[(long)(tid + r * 256) * 8];
    }

    for (int ks = 0; ks < 13; ++ks) {
        // ---- stage x: convert regs -> fp16 hi/lo, ds_write (swizzled)
        float va[8] = {xr0.x, xr0.y, xr0.z, xr0.w, xr1.x, xr1.y, xr1.z, xr1.w};
        us8 hi8, lo8;
        #pragma unroll
        for (int j = 0; j < 8; ++j) {
            _Float16 h = (_Float16)va[j];
            hi8[j] = h2b(h);
            lo8[j] = h2b((_Float16)(va[j] - (float)h));
        }
        int xpos = sr * 32 + ((skc * 8) ^ ((sr & 3) << 3));
        *(us8*)&xsh[xpos] = hi8;
        *(us8*)&xsl[xpos] = lo8;
        // ---- stage W from regs
        #pragma unroll
        for (int r = 0; r < 4; ++r) {
            int u = tid + r * 256;
            u16* dst = (u >> 9) ? wsl : wsh;
            *(us8*)&dst[(u & 511) * 8] = wr[r];
        }
        // ---- issue prefetch for ks+1 (stays in flight across barrier)
        if (ks + 1 < 13) {
            if ((ks + 1) * 32 + skc * 8 < 400) {
                const float* xp = x + (row0 + sr) * 400 + (ks + 1) * 32 + skc * 8;
                xr0 = *(const float4*)xp;
                xr1 = *(const float4*)(xp + 4);
            } else {
                xr0 = make_float4(0.f, 0.f, 0.f, 0.f);
                xr1 = make_float4(0.f, 0.f, 0.f, 0.f);
            }
            const u16* wsrc = wbase + (long)(ks + 1) * 8192;
            #pragma unroll
            for (int r = 0; r < 4; ++r)
                wr[r] = *(const us8*)&wsrc[(long)(tid + r * 256) * 8];
        }
        BAR();
        // ---- MFMA
        const int arow = w * 16 + c15;
        const int axo = arow * 32 + ((g * 8) ^ ((arow & 3) << 3));
        f16x8 ah = *(const f16x8*)&xsh[axo];
        f16x8 al = *(const f16x8*)&xsl[axo];
        __builtin_amdgcn_s_setprio(1);
        #pragma unroll
        for (int nt = 0; nt < 8; ++nt) {
            int brow = nt * 16 + c15;
            int boff = brow * 32 + ((g * 8) ^ ((brow & 3) << 3));
            f16x8 bh = *(const f16x8*)&wsh[boff];
            acc[nt] = __builtin_amdgcn_mfma_f32_16x16x32_f16(ah, bh, acc[nt], 0, 0, 0);
            acc[nt] = __builtin_amdgcn_mfma_f32_16x16x32_f16(al, bh, acc[nt], 0, 0, 0);
            if (m != 2) {
                f16x8 bl = *(const f16x8*)&wsl[boff];
                acc[nt] = __builtin_amdgcn_mfma_f32_16x16x32_f16(ah, bl, acc[nt], 0, 0, 0);
            }
        }
        __builtin_amdgcn_s_setprio(0);
        BAR();
    }

    if (m == 2) {
        // deposit transposed V image: epi[d][q] with XOR(q ^ 8*(d&7))
        #pragma unroll
        for (int nt = 0; nt < 8; ++nt) {
            int d = nt * 16 + c15;
            int q0 = w * 16 + 4 * g;
            us4 v4;
            #pragma unroll
            for (int r = 0; r < 4; ++r) v4[r] = h2b((_Float16)acc[nt][r]);
            *(us4*)&epi[d * 64 + (q0 ^ ((d & 7) << 3))] = v4;
        }
        __syncthreads();
        u16* dst = VT + (long)rowblk * 8192;    // linear dump = swizzled image
        #pragma unroll
        for (int r = 0; r < 4; ++r) {
            int u = tid + r * 256;
            *(us8*)&dst[(long)u * 8] = *(const us8*)&epi[u * 8];
        }
    } else {
        const float qs = (m == 0) ? 0.14426950408889634f : 1.0f;
        #pragma unroll
        for (int nt = 0; nt < 8; ++nt) {
            #pragma unroll
            for (int r = 0; r < 4; ++r) {
                int row = w * 16 + 4 * g + r, col = nt * 16 + c15;
                epi[row * 128 + (col ^ ((row & 7) << 3))] =
                    h2b((_Float16)(acc[nt][r] * qs));
            }
        }
        __syncthreads();
        if (m == 0) {
            // Q: un-swizzle to plain row-major (flash reads frags directly)
            #pragma unroll
            for (int r = 0; r < 4; ++r) {
                int u = tid + r * 256;
                int row = u >> 4, c = u & 15;
                *(us8*)&QH[(row0 + row) * 128 + c * 8] =
                    *(const us8*)&epi[row * 128 + ((c * 8) ^ ((row & 7) << 3))];
            }
        } else {
            u16* dst = KH + (long)rowblk * 8192; // linear dump = swizzled image
            #pragma unroll
            for (int r = 0; r < 4; ++r) {
                int u = tid + r * 256;
                *(us8*)&dst[(long)u * 8] = *(const us8*)&epi[u * 8];
            }
        }
        if (m == 1) {
            __syncthreads();
            #pragma unroll
            for (int nt = 0; nt < 8; ++nt) {
                #pragma unroll
                for (int r = 0; r < 4; ++r) {
                    int row = w * 16 + 4 * g + r, col = nt * 16 + c15;
                    // (unused lo image slot kept for layout compat; skip)
                }
            }
        }
    }
}

// ---------------- fp16 MFMA flash attention, prefetch-pipelined, KV-split x2
// grid (32, 16, 2), block 256 (4 waves x 16 q).
__global__ __launch_bounds__(256) void k_flash(
    const u16* __restrict__ Qg, const u16* __restrict__ Kg,
    const u16* __restrict__ Vg, u16* __restrict__ VOI,
    float2* __restrict__ ML) {
    __shared__ __align__(16) char KS[16384];     // K tile image [64r][16c]
    __shared__ __align__(16) char VS[16384];     // V^T tile image [128d][8c]
    __shared__ __align__(16) char PS[4][2048];   // per-wave P [16q][64k] (+sc/l alias)

    const int tid = threadIdx.x;
    const int w = tid >> 6, l = tid & 63, g = l >> 4, c15 = l & 15;
    const int b = blockIdx.y, qt = blockIdx.x, half = blockIdx.z;
    const int t0 = half * 16;

    const u16* qp = Qg + ((long)b * 2048 + qt * 64 + w * 16 + c15) * 128;
    f16x8 qh[4];
    #pragma unroll
    for (int ks = 0; ks < 4; ++ks) qh[ks] = *(const f16x8*)(qp + ks * 32 + g * 8);

    f4v O[7];
    #pragma unroll
    for (int i = 0; i < 7; ++i) O[i] = (f4v){0.f, 0.f, 0.f, 0.f};
    float mrow = -1e30f, lrow = 0.f;

    const u16* Kb = Kg + (long)b * 32 * 8192;
    const u16* Vb = Vg + (long)b * 32 * 8192;
    char* Pw = PS[w];

    // prologue: prefetch first tile into regs
    us8 kreg[4], vreg[4];
    #pragma unroll
    for (int r = 0; r < 4; ++r) {
        kreg[r] = *(const us8*)(Kb + (long)t0 * 8192 + (long)(tid + r * 256) * 8);
        vreg[r] = *(const us8*)(Vb + (long)t0 * 8192 + (long)(tid + r * 256) * 8);
    }

    for (int t = t0; t < t0 + 16; ++t) {
        // ---- ds_write prefetched tile (compiler waits the exact vmcnt)
        #pragma unroll
        for (int r = 0; r < 4; ++r) {
            *(us8*)(KS + (tid + r * 256) * 16) = kreg[r];
            *(us8*)(VS + (tid + r * 256) * 16) = vreg[r];
        }
        // ---- issue next tile's loads; they stay in flight across barriers
        if (t + 1 < t0 + 16) {
            #pragma unroll
            for (int r = 0; r < 4; ++r) {
                kreg[r] = *(const us8*)(Kb + (long)(t + 1) * 8192 +
                                        (long)(tid + r * 256) * 8);
                vreg[r] = *(const us8*)(Vb + (long)(t + 1) * 8192 +
                                        (long)(tid + r * 256) * 8);
            }
        }
        BAR();

        // ---- S^T = K Q^T: lane (g,c15) reg (nt,r) = S[q=c15][key=16nt+4g+r]
        f4v s[4];
        #pragma unroll
        for (int nt = 0; nt < 4; ++nt) s[nt] = (f4v){0.f, 0.f, 0.f, 0.f};
        __builtin_amdgcn_s_setprio(1);
        #pragma unroll
        for (int ks = 0; ks < 4; ++ks) {
            #pragma unroll
            for (int nt = 0; nt < 4; ++nt) {
                int key = nt * 16 + c15;
                f16x8 kf = *(const f16x8*)(KS + key * 256 +
                                           ((ks * 64 + g * 16) ^ ((key & 7) << 4)));
                s[nt] = __builtin_amdgcn_mfma_f32_16x16x32_f16(kf, qh[ks], s[nt], 0, 0, 0);
            }
        }
        __builtin_amdgcn_s_setprio(0);

        // ---- online softmax, q = c15 (keys split over g)
        float mx = s[0][0];
        #pragma unroll
        for (int nt = 0; nt < 4; ++nt) {
            #pragma unroll
            for (int r = 0; r < 4; ++r) mx = fmaxf(mx, s[nt][r]);
        }
        mx = fmaxf(mx, __shfl_xor(mx, 16));
        mx = fmaxf(mx, __shfl_xor(mx, 32));
        if (!__all(mx <= mrow)) {
            float mnew = fmaxf(mrow, mx);
            float sc = exp2f(mrow - mnew);
            mrow = mnew;
            lrow *= sc;
            if (g == 0) ((float*)Pw)[c15] = sc;     // alias into PS (pre-P-write)
            float s0 = ((float*)Pw)[4 * g + 0];
            float s1 = ((float*)Pw)[4 * g + 1];
            float s2 = ((float*)Pw)[4 * g + 2];
            float s3 = ((float*)Pw)[4 * g + 3];
            #pragma unroll
            for (int dt = 0; dt < 7; ++dt) {
                O[dt][0] *= s0; O[dt][1] *= s1; O[dt][2] *= s2; O[dt][3] *= s3;
            }
        }
        float sum = 0.f;
        #pragma unroll
        for (int nt = 0; nt < 4; ++nt) {
            #pragma unroll
            for (int r = 0; r < 4; ++r) {
                float p = exp2f(s[nt][r] - mrow);   // Q pre-scaled by 0.1*log2e
                s[nt][r] = p;
                sum += p;
            }
        }
        sum += __shfl_xor(sum, 16);
        sum += __shfl_xor(sum, 32);
        lrow += sum;

        // ---- P -> per-wave swizzled LDS (packed 4x fp16 per write)
        #pragma unroll
        for (int nt = 0; nt < 4; ++nt) {
            us4 pw;
            #pragma unroll
            for (int r = 0; r < 4; ++r) pw[r] = h2b((_Float16)s[nt][r]);
            *(us4*)(Pw + c15 * 128 + ((32 * nt + 8 * g) ^ ((c15 & 7) << 4))) = pw;
        }
        // ---- PV: O[16q][112d] += P[16q][64k] V[64k][d]
        __builtin_amdgcn_s_setprio(1);
        #pragma unroll
        for (int k0 = 0; k0 < 2; ++k0) {
            f16x8 pa = *(const f16x8*)(Pw + c15 * 128 +
                                       ((k0 * 64 + g * 16) ^ ((c15 & 7) << 4)));
            #pragma unroll
            for (int dt = 0; dt < 7; ++dt) {
                int d = dt * 16 + c15;
                f16x8 vf = *(const f16x8*)(VS + d * 128 +
                                           ((k0 * 64 + g * 16) ^ ((d & 7) << 4)));
                O[dt] = __builtin_amdgcn_mfma_f32_16x16x32_f16(pa, vf, O[dt], 0, 0, 0);
            }
        }
        __builtin_amdgcn_s_setprio(0);
        BAR();
    }

    // ---- l-normalize + store fp16 partial image [half][b][qt][64r][16chunk]
    if (g == 0) {
        ((float*)Pw)[c15] = lrow;
        ML[half * 32768 + b * 2048 + qt * 64 + w * 16 + c15] =
            make_float2(mrow, lrow);
    }
    float linv[4];
    #pragma unroll
    for (int r = 0; r < 4; ++r) linv[r] = 1.f / ((float*)Pw)[4 * g + r];
    u16* vout = VOI + (long)half * 4194304 + ((long)b * 32 + qt) * 8192;
    #pragma unroll
    for (int r = 0; r < 4; ++r) {
        int rowl = w * 16 + 4 * g + r;
        int rsw = (4 * g + r) & 7;
        #pragma unroll
        for (int dt = 0; dt < 7; ++dt) {
            int d = dt * 16 + c15;
            int pos = rowl * 128 + ((((d >> 3) ^ rsw) << 3) | (d & 7));
            vout[pos] = h2b((_Float16)(O[dt][r] * linv[r]));
        }
        int dz = 112 + c15;
        vout[rowl * 128 + ((((dz >> 3) ^ rsw) << 3) | (dz & 7))] = 0;
    }
}

// ---------------- h = relu(VO@W2 + d1_b) via MFMA; fused half-combine ------
__global__ __launch_bounds__(256) void k_hpool(
    const u16* __restrict__ VOI, const float2* __restrict__ ML,
    const u16* __restrict__ W2F, const float* __restrict__ d1b,
    float* __restrict__ pmax, float* __restrict__ psum) {
    __shared__ __align__(16) u16 A[8192];
    __shared__ float redM[4][400], redS[4][400];
    __shared__ float wgt[64][2];
    const int tid = threadIdx.x;
    const int w = tid >> 6, l = tid & 63, g = l >> 4, c15 = l & 15;
    const int b = blockIdx.y, rt = blockIdx.x;

    if (tid < 64) {
        float2 a = ML[b * 2048 + rt * 64 + tid];
        float2 c = ML[32768 + b * 2048 + rt * 64 + tid];
        float m = fmaxf(a.x, c.x);
        float w1 = exp2f(a.x - m) * a.y;
        float w2 = exp2f(c.x - m) * c.y;
        float inv = 1.f / (w1 + w2);
        wgt[tid][0] = w1 * inv;
        wgt[tid][1] = w2 * inv;
    }
    __syncthreads();

    const u16* s1 = VOI + ((long)b * 32 + rt) * 8192;
    const u16* s2 = s1 + 4194304;
    #pragma unroll
    for (int r = 0; r < 4; ++r) {
        int u = tid + r * 256;
        int row = u >> 4;
        us8 p1 = *(const us8*)&s1[(long)u * 8];
        us8 p2 = *(const us8*)&s2[(long)u * 8];
        float w1 = wgt[row][0], w2 = wgt[row][1];
        us8 o;
        #pragma unroll
        for (int j = 0; j < 8; ++j)
            o[j] = h2b((_Float16)(w1 * b2f(p1[j]) + w2 * b2f(p2[j])));
        *(us8*)&A[u * 8] = o;
    }
    __syncthreads();

    const int arow = w * 16 + c15;
    f16x8 af[4];
    #pragma unroll
    for (int ks = 0; ks < 4; ++ks)
        af[ks] = *(const f16x8*)&A[arow * 128 + ((ks * 32 + g * 8) ^ ((arow & 7) << 3))];

    for (int nt = 0; nt < 25; ++nt) {
        f4v acc = (f4v){0.f, 0.f, 0.f, 0.f};
        #pragma unroll
        for (int ks = 0; ks < 4; ++ks) {
            f16x8 bf = *(const f16x8*)&W2F[(nt * 4 + ks) * 512 + l * 8];
            acc = __builtin_amdgcn_mfma_f32_16x16x32_f16(af[ks], bf, acc, 0, 0, 0);
        }
        float bias = d1b[nt * 16 + c15];
        float mx4 = -1e30f, sm4 = 0.f;
        #pragma unroll
        for (int r = 0; r < 4; ++r) {
            float h = fmaxf(acc[r] + bias, 0.f);
            mx4 = fmaxf(mx4, h);
            sm4 += h;
        }
        mx4 = fmaxf(mx4, __shfl_xor(mx4, 16));
        mx4 = fmaxf(mx4, __shfl_xor(mx4, 32));
        sm4 += __shfl_xor(sm4, 16);
        sm4 += __shfl_xor(sm4, 32);
        if (g == 0) {
            redM[w][nt * 16 + c15] = mx4;
            redS[w][nt * 16 + c15] = sm4;
        }
    }
    __syncthreads();
    for (int j = tid; j < 400; j += 256) {
        float mx = fmaxf(fmaxf(redM[0][j], redM[1][j]), fmaxf(redM[2][j], redM[3][j]));
        float sm = redS[0][j] + redS[1][j] + redS[2][j] + redS[3][j];
        pmax[((long)b * 32 + rt) * 400 + j] = mx;
        psum[((long)b * 32 + rt) * 400 + j] = sm;
    }
}

// ---------------- reduce partials -> pooled[b][800] ------------------------
__global__ void k_pred(const float* __restrict__ pmax, const float* __restrict__ psum,
                       float* __restrict__ pooled) {
    const int b = blockIdx.x;
    for (int j = threadIdx.x; j < 400; j += 256) {
        float mx = -1e30f, sm = 0.f;
        for (int t = 0; t < 32; ++t) {
            mx = fmaxf(mx, pmax[((long)b * 32 + t) * 400 + j]);
            sm += psum[((long)b * 32 + t) * 400 + j];
        }
        pooled[b * 800 + j] = mx;
        pooled[b * 800 + 400 + j] = sm * (1.f / 2048.f);
    }
}

// ---------------- fc1 / fc2 ------------------------------------------------
__global__ void k_fc1(const float* __restrict__ pooled, const float* __restrict__ w,
                      const float* __restrict__ bias, float* __restrict__ out) {
    const int b = blockIdx.x, j = threadIdx.x;
    float acc = bias[j];
    for (int k = 0; k < 800; ++k) acc += pooled[b * 800 + k] * w[k * 512 + j];
    out[b * 512 + j] = fmaxf(acc, 0.f);
}

__global__ void k_fc2(const float* __restrict__ h, const float* __restrict__ w,
                      const float* __restrict__ bias, float* __restrict__ out) {
    const int b = blockIdx.x, j = threadIdx.x;
    float acc = bias[j];
    for (int k = 0; k < 512; ++k) acc += h[b * 512 + k] * w[k * 256 + j];
    out[b * 256 + j] = fmaxf(acc, 0.f);
}

extern "C" void kernel_launch(void* const* d_in, const int* in_sizes, int n_in,
                              void* d_out, int out_size, void* d_ws, size_t ws_size,
                              hipStream_t stream) {
    const float* x          = (const float*)d_in[0];
    const float* attn_kernel= (const float*)d_in[1];
    const float* attn_dense = (const float*)d_in[2];
    const float* d1_w       = (const float*)d_in[3];
    const float* d1_b       = (const float*)d_in[4];
    const float* fc1_w      = (const float*)d_in[5];
    const float* fc1_b      = (const float*)d_in[6];
    const float* fc2_w      = (const float*)d_in[7];
    const float* fc2_b      = (const float*)d_in[8];
    float* out = (float*)d_out;
    char*  wsb = (char*)d_ws;

    // ws layout (bytes), total ~44.9 MB
    u16*    QH   = (u16*)(wsb);                    //  8,388,608
    u16*    KH   = (u16*)(wsb + 8388608);          //  8,388,608 (tile images)
    u16*    VT   = (u16*)(wsb + 16777216);         //  8,388,608 (tile images)
    u16*    VOI  = (u16*)(wsb + 25165824);         // 16,777,216 (2 half-images)
    u16*    WSP  = (u16*)(wsb + 41943040);         //    638,976
    u16*    W2F  = (u16*)(wsb + 42582016);         //    102,400
    float*  ADF  = (float*)(wsb + 42684416);       //    160,000
    float*  PMAX = (float*)(wsb + 42844416);       //    819,200
    float*  PSUM = (float*)(wsb + 43663616);       //    819,200
    float*  POOL = (float*)(wsb + 44482816);       //     51,200
    float*  FC1  = (float*)(wsb + 44534016);       //     32,768
    float2* ML   = (float2*)(wsb + 44566784);      //    524,288

    k_wprep<<<624, 256, 0, stream>>>(attn_kernel, WSP);
    k_fold<<<157, 256, 0, stream>>>(attn_dense, ADF);
    k_w2f <<<200, 256, 0, stream>>>(ADF, d1_w, W2F);
    k_gemm_qkv<<<1536, 256, 0, stream>>>(x, WSP, QH, KH, VT);
    k_flash<<<dim3(32, 16, 2), 256, 0, stream>>>(QH, KH, VT, VOI, ML);
    k_hpool<<<dim3(32, 16), 256, 0, stream>>>(VOI, ML, W2F, d1_b, PMAX, PSUM);
    k_pred<<<16, 256, 0, stream>>>(PMAX, PSUM, POOL);
    k_fc1 <<<16, 512, 0, stream>>>(POOL, fc1_w, fc1_b, FC1);
    k_fc2 <<<16, 256, 0, stream>>>(FC1, fc2_w, fc2_b, out);
}

// Round 7
// 213.358 us; speedup vs baseline: 6.9794x; 1.0847x over previous
//
#include <hip/hip_runtime.h>

typedef __attribute__((ext_vector_type(8))) _Float16 f16x8;
typedef __attribute__((ext_vector_type(2))) _Float16 h2v;
typedef __attribute__((ext_vector_type(4))) float f4v;
typedef __attribute__((ext_vector_type(8))) unsigned short us8;
typedef __attribute__((ext_vector_type(4))) unsigned short us4;
typedef unsigned short u16;

__device__ __forceinline__ u16 h2b(_Float16 h) { return __builtin_bit_cast(u16, h); }
__device__ __forceinline__ float b2f(u16 b) {
    return (float)__builtin_bit_cast(_Float16, b);
}

// Raw barrier: drain LDS ops only; leave prefetch global loads in flight.
#define BAR() do { asm volatile("s_waitcnt lgkmcnt(0)" ::: "memory"); \
                   __builtin_amdgcn_s_barrier(); } while (0)

// ---------------- fold attn_dense: AD_f[h][e] = sum_k ad[k*100+h][e] -------
__global__ void k_fold(const float* __restrict__ ad, float* __restrict__ adf) {
    int i = blockIdx.x * 256 + threadIdx.x;
    if (i < 100 * 400) {
        int h = i / 400, e = i % 400;
        float s = 0.f;
        #pragma unroll
        for (int k = 0; k < 4; ++k) s += ad[(k * 100 + h) * 400 + e];
        adf[i] = s;
    }
}

// ---- W2 partials: e-split x4 (each block-slice sums 100 of 400 e's) -------
__global__ void k_w2p(const float* __restrict__ adf, const float* __restrict__ d1w,
                      float* __restrict__ w2p) {
    int i = blockIdx.x * 256 + threadIdx.x;       // 128 d x 400 j
    if (i >= 51200) return;
    int es = blockIdx.y;
    int d = i / 400, j = i % 400;
    float acc = 0.f;
    if (d < 100) {
        const float* ar = adf + d * 400 + es * 100;
        const float* wr = d1w + (es * 100) * 400 + j;
        #pragma unroll 4
        for (int e = 0; e < 100; ++e) acc += ar[e] * wr[e * 400];
    }
    w2p[es * 51200 + i] = acc;
}

// ---- reduce partials, pack to fp16 MFMA B-fragments [25 nt][4 ks][64][8] --
__global__ void k_w2r(const float* __restrict__ w2p, u16* __restrict__ w2f) {
    int i = blockIdx.x * 256 + threadIdx.x;
    if (i >= 51200) return;
    float acc = w2p[i] + w2p[51200 + i] + w2p[102400 + i] + w2p[153600 + i];
    int d = i / 400, j = i % 400;
    int idx = ((j >> 4) * 4 + (d >> 5)) * 512 + (((d >> 3) & 3) * 16 + (j & 15)) * 8 + (d & 7);
    w2f[idx] = h2b((_Float16)acc);
}

// ---- W prep: fp16 hi/lo tiles [3 m][13 ks][2 hl][128 n][32 k], x-swizzled -
__global__ void k_wprep(const float* __restrict__ ak, u16* __restrict__ wsp) {
    int i = blockIdx.x * 256 + threadIdx.x;       // 3*13*4096 = 159744
    if (i >= 159744) return;
    int k = i & 31, n = (i >> 5) & 127;
    int xx = i >> 12;                             // m*13 + ks
    int ks = xx % 13, m = xx / 13;
    int gk = ks * 32 + k;
    float v = (n < 100 && gk < 400) ? ak[m * 40000 + gk * 100 + n] : 0.f;
    _Float16 hb = (_Float16)v;
    _Float16 lb = (_Float16)(v - (float)hb);
    long base = (long)xx * 8192;
    int pos = n * 32 + ((((k >> 3) ^ (n & 3)) << 3) | (k & 7));
    wsp[base + pos] = h2b(hb);
    wsp[base + 4096 + pos] = h2b(lb);
}

// ---------------- QKV via fp16 MFMA, dbuf + reg-prefetch, 1 BAR/iter -------
// grid 1536 (m = bx%3), block 256 (4 waves, 64 rows).
__global__ __launch_bounds__(256) void k_gemm_qkv(
    const float* __restrict__ x, const u16* __restrict__ wsp,
    u16* __restrict__ QH, u16* __restrict__ KH, u16* __restrict__ VT) {
    __shared__ __align__(16) u16 smem[24576];     // 2 x 24KB bufs; epi aliases

    const int tid = threadIdx.x;
    const int bx = blockIdx.x;
    const int m = bx % 3;
    const int rowblk = bx / 3;
    const long row0 = (long)rowblk * 64;
    const int w = tid >> 6, l = tid & 63, g = l >> 4, c15 = l & 15;
    const int sr = tid >> 2, skc = tid & 3;

    f4v acc[8];
    #pragma unroll
    for (int nt = 0; nt < 8; ++nt) acc[nt] = (f4v){0.f, 0.f, 0.f, 0.f};

    const u16* wbase = wsp + (long)m * 13 * 8192;

    float4 xr0, xr1;
    us8 wr[4];
    const int xpos = sr * 32 + ((skc * 8) ^ ((sr & 3) << 3));

    // ---- prologue: load ks=0, stage into buf0, load ks=1
    {
        const float* xp = x + (row0 + sr) * 400 + skc * 8;
        xr0 = *(const float4*)xp;
        xr1 = *(const float4*)(xp + 4);
        #pragma unroll
        for (int r = 0; r < 4; ++r)
            wr[r] = *(const us8*)&wbase[(long)(tid + r * 256) * 8];
        float va[8] = {xr0.x, xr0.y, xr0.z, xr0.w, xr1.x, xr1.y, xr1.z, xr1.w};
        us8 hi8, lo8;
        #pragma unroll
        for (int j = 0; j < 8; ++j) {
            _Float16 h = (_Float16)va[j];
            hi8[j] = h2b(h);
            lo8[j] = h2b((_Float16)(va[j] - (float)h));
        }
        *(us8*)&smem[xpos] = hi8;
        *(us8*)&smem[2048 + xpos] = lo8;
        #pragma unroll
        for (int r = 0; r < 4; ++r) {
            int u = tid + r * 256;
            *(us8*)&smem[4096 + (u >> 9) * 4096 + (u & 511) * 8] = wr[r];
        }
        const float* xp1 = x + (row0 + sr) * 400 + 32 + skc * 8;
        xr0 = *(const float4*)xp1;
        xr1 = *(const float4*)(xp1 + 4);
        const u16* wsrc = wbase + 8192;
        #pragma unroll
        for (int r = 0; r < 4; ++r)
            wr[r] = *(const us8*)&wsrc[(long)(tid + r * 256) * 8];
    }

    for (int ks = 0; ks < 13; ++ks) {
        BAR();
        u16* cb = smem + (ks & 1) * 12288;         // compute buf (tile ks)
        u16* sb = smem + ((ks & 1) ^ 1) * 12288;   // stage buf (tile ks+1)
        if (ks + 1 < 13) {
            float va[8] = {xr0.x, xr0.y, xr0.z, xr0.w, xr1.x, xr1.y, xr1.z, xr1.w};
            us8 hi8, lo8;
            #pragma unroll
            for (int j = 0; j < 8; ++j) {
                _Float16 h = (_Float16)va[j];
                hi8[j] = h2b(h);
                lo8[j] = h2b((_Float16)(va[j] - (float)h));
            }
            *(us8*)&sb[xpos] = hi8;
            *(us8*)&sb[2048 + xpos] = lo8;
            #pragma unroll
            for (int r = 0; r < 4; ++r) {
                int u = tid + r * 256;
                *(us8*)&sb[4096 + (u >> 9) * 4096 + (u & 511) * 8] = wr[r];
            }
            if (ks + 2 < 13) {
                if ((ks + 2) * 32 + skc * 8 < 400) {
                    const float* xp = x + (row0 + sr) * 400 + (ks + 2) * 32 + skc * 8;
                    xr0 = *(const float4*)xp;
                    xr1 = *(const float4*)(xp + 4);
                } else {
                    xr0 = make_float4(0.f, 0.f, 0.f, 0.f);
                    xr1 = make_float4(0.f, 0.f, 0.f, 0.f);
                }
                const u16* wsrc = wbase + (long)(ks + 2) * 8192;
                #pragma unroll
                for (int r = 0; r < 4; ++r)
                    wr[r] = *(const us8*)&wsrc[(long)(tid + r * 256) * 8];
            }
        }
        // ---- MFMA on compute buf
        const int arow = w * 16 + c15;
        const int axo = arow * 32 + ((g * 8) ^ ((arow & 3) << 3));
        f16x8 ah = *(const f16x8*)&cb[axo];
        f16x8 al = *(const f16x8*)&cb[2048 + axo];
        __builtin_amdgcn_s_setprio(1);
        #pragma unroll
        for (int nt = 0; nt < 8; ++nt) {
            int brow = nt * 16 + c15;
            int boff = brow * 32 + ((g * 8) ^ ((brow & 3) << 3));
            f16x8 bh = *(const f16x8*)&cb[4096 + boff];
            acc[nt] = __builtin_amdgcn_mfma_f32_16x16x32_f16(ah, bh, acc[nt], 0, 0, 0);
            acc[nt] = __builtin_amdgcn_mfma_f32_16x16x32_f16(al, bh, acc[nt], 0, 0, 0);
            if (m != 2) {
                f16x8 bl = *(const f16x8*)&cb[8192 + boff];
                acc[nt] = __builtin_amdgcn_mfma_f32_16x16x32_f16(ah, bl, acc[nt], 0, 0, 0);
            }
        }
        __builtin_amdgcn_s_setprio(0);
    }
    BAR();
    u16* epi = smem;                               // alias buf0 (safe post-BAR)

    if (m == 2) {
        // deposit transposed V image: epi[d][q] with XOR(q ^ 8*(d&7))
        #pragma unroll
        for (int nt = 0; nt < 8; ++nt) {
            int d = nt * 16 + c15;
            int q0 = w * 16 + 4 * g;
            us4 v4;
            #pragma unroll
            for (int r = 0; r < 4; ++r) v4[r] = h2b((_Float16)acc[nt][r]);
            *(us4*)&epi[d * 64 + (q0 ^ ((d & 7) << 3))] = v4;
        }
        __syncthreads();
        u16* dst = VT + (long)rowblk * 8192;    // linear dump = swizzled image
        #pragma unroll
        for (int r = 0; r < 4; ++r) {
            int u = tid + r * 256;
            if (u < 896)                         // d rows >= 112 never read
                *(us8*)&dst[(long)u * 8] = *(const us8*)&epi[u * 8];
        }
    } else {
        const float qs = (m == 0) ? 0.14426950408889634f : 1.0f;
        #pragma unroll
        for (int nt = 0; nt < 8; ++nt) {
            #pragma unroll
            for (int r = 0; r < 4; ++r) {
                int row = w * 16 + 4 * g + r, col = nt * 16 + c15;
                epi[row * 128 + (col ^ ((row & 7) << 3))] =
                    h2b((_Float16)(acc[nt][r] * qs));
            }
        }
        __syncthreads();
        if (m == 0) {
            // Q: un-swizzle to plain row-major (flash reads frags directly)
            #pragma unroll
            for (int r = 0; r < 4; ++r) {
                int u = tid + r * 256;
                int row = u >> 4, c = u & 15;
                *(us8*)&QH[(row0 + row) * 128 + c * 8] =
                    *(const us8*)&epi[row * 128 + ((c * 8) ^ ((row & 7) << 3))];
            }
        } else {
            u16* dst = KH + (long)rowblk * 8192; // linear dump = swizzled image
            #pragma unroll
            for (int r = 0; r < 4; ++r) {
                int u = tid + r * 256;
                *(us8*)&dst[(long)u * 8] = *(const us8*)&epi[u * 8];
            }
        }
    }
}

// ---------------- fp16 MFMA flash attention, dbuf, no-max softmax ----------
// grid (32, 16, 2), block 256 (4 waves x 16 q). 1 barrier per KV tile.
// Logits bounded (|S*scale*log2e| < ~12) -> exp2 directly, no max tracking.
__global__ __launch_bounds__(256) void k_flash(
    const u16* __restrict__ Qg, const u16* __restrict__ Kg,
    const u16* __restrict__ Vg, u16* __restrict__ VOI,
    float* __restrict__ ML) {
    __shared__ __align__(16) char KS[2][16384];  // K tile image [64r][16c]
    __shared__ __align__(16) char VS[2][14336];  // V^T tile image [112d][8c]
    __shared__ __align__(16) char PS[4][2048];   // per-wave P [16q][64k] (+l alias)

    const int tid = threadIdx.x;
    const int w = tid >> 6, l = tid & 63, g = l >> 4, c15 = l & 15;
    const int b = blockIdx.y, qt = blockIdx.x, half = blockIdx.z;
    const int t0 = half * 16;

    const u16* qp = Qg + ((long)b * 2048 + qt * 64 + w * 16 + c15) * 128;
    f16x8 qh[4];
    #pragma unroll
    for (int ks = 0; ks < 4; ++ks) qh[ks] = *(const f16x8*)(qp + ks * 32 + g * 8);

    f4v O[7];
    #pragma unroll
    for (int i = 0; i < 7; ++i) O[i] = (f4v){0.f, 0.f, 0.f, 0.f};
    float lrow = 0.f;

    const u16* Kb = Kg + (long)b * 32 * 8192;
    const u16* Vb = Vg + (long)b * 32 * 8192;
    char* Pw = PS[w];

    // ---- prologue: stage tile t0 into buf0; prefetch t0+1 into regs
    us8 kreg[4], vreg[4];
    #pragma unroll
    for (int r = 0; r < 4; ++r) {
        int u = tid + r * 256;
        kreg[r] = *(const us8*)(Kb + (long)t0 * 8192 + (long)u * 8);
        if (u < 896) vreg[r] = *(const us8*)(Vb + (long)t0 * 8192 + (long)u * 8);
    }
    #pragma unroll
    for (int r = 0; r < 4; ++r) {
        int u = tid + r * 256;
        *(us8*)(KS[0] + u * 16) = kreg[r];
        if (u < 896) *(us8*)(VS[0] + u * 16) = vreg[r];
    }
    #pragma unroll
    for (int r = 0; r < 4; ++r) {
        int u = tid + r * 256;
        kreg[r] = *(const us8*)(Kb + (long)(t0 + 1) * 8192 + (long)u * 8);
        if (u < 896) vreg[r] = *(const us8*)(Vb + (long)(t0 + 1) * 8192 + (long)u * 8);
    }

    for (int t = t0; t < t0 + 16; ++t) {
        const int cur = (t - t0) & 1;
        BAR();   // buf[cur] writes visible; buf[cur^1] readers (t-1) done
        // ---- stage tile t+1 into buf^1 from regs; issue loads for t+2
        if (t + 1 < t0 + 16) {
            #pragma unroll
            for (int r = 0; r < 4; ++r) {
                int u = tid + r * 256;
                *(us8*)(KS[cur ^ 1] + u * 16) = kreg[r];
                if (u < 896) *(us8*)(VS[cur ^ 1] + u * 16) = vreg[r];
            }
            if (t + 2 < t0 + 16) {
                #pragma unroll
                for (int r = 0; r < 4; ++r) {
                    int u = tid + r * 256;
                    kreg[r] = *(const us8*)(Kb + (long)(t + 2) * 8192 + (long)u * 8);
                    if (u < 896)
                        vreg[r] = *(const us8*)(Vb + (long)(t + 2) * 8192 + (long)u * 8);
                }
            }
        }
        const char* Kc = KS[cur];
        const char* Vc = VS[cur];

        // ---- S^T = K Q^T: lane (g,c15) reg (nt,r) = S[q=c15][key=16nt+4g+r]
        f4v s[4];
        #pragma unroll
        for (int nt = 0; nt < 4; ++nt) s[nt] = (f4v){0.f, 0.f, 0.f, 0.f};
        __builtin_amdgcn_s_setprio(1);
        #pragma unroll
        for (int ks = 0; ks < 4; ++ks) {
            #pragma unroll
            for (int nt = 0; nt < 4; ++nt) {
                int key = nt * 16 + c15;
                f16x8 kf = *(const f16x8*)(Kc + key * 256 +
                                           ((ks * 64 + g * 16) ^ ((key & 7) << 4)));
                s[nt] = __builtin_amdgcn_mfma_f32_16x16x32_f16(kf, qh[ks], s[nt], 0, 0, 0);
            }
        }
        __builtin_amdgcn_s_setprio(0);

        // ---- softmax numerators (no max shift needed; logits bounded)
        float sum = 0.f;
        #pragma unroll
        for (int nt = 0; nt < 4; ++nt) {
            #pragma unroll
            for (int r = 0; r < 4; ++r) {
                float p = exp2f(s[nt][r]);          // Q pre-scaled by 0.1*log2e
                s[nt][r] = p;
                sum += p;
            }
        }
        sum += __shfl_xor(sum, 16);
        sum += __shfl_xor(sum, 32);
        lrow += sum;

        // ---- P -> per-wave swizzled LDS (packed cvt_pkrtz pairs)
        #pragma unroll
        for (int nt = 0; nt < 4; ++nt) {
            uint2 pw2;
            pw2.x = __builtin_bit_cast(unsigned int,
                        __builtin_amdgcn_cvt_pkrtz(s[nt][0], s[nt][1]));
            pw2.y = __builtin_bit_cast(unsigned int,
                        __builtin_amdgcn_cvt_pkrtz(s[nt][2], s[nt][3]));
            *(uint2*)(Pw + c15 * 128 + ((32 * nt + 8 * g) ^ ((c15 & 7) << 4))) = pw2;
        }
        // ---- PV: O[16q][112d] += P[16q][64k] V[64k][d]
        __builtin_amdgcn_s_setprio(1);
        #pragma unroll
        for (int k0 = 0; k0 < 2; ++k0) {
            f16x8 pa = *(const f16x8*)(Pw + c15 * 128 +
                                       ((k0 * 64 + g * 16) ^ ((c15 & 7) << 4)));
            #pragma unroll
            for (int dt = 0; dt < 7; ++dt) {
                int d = dt * 16 + c15;
                f16x8 vf = *(const f16x8*)(Vc + d * 128 +
                                           ((k0 * 64 + g * 16) ^ ((d & 7) << 4)));
                O[dt] = __builtin_amdgcn_mfma_f32_16x16x32_f16(pa, vf, O[dt], 0, 0, 0);
            }
        }
        __builtin_amdgcn_s_setprio(0);
    }

    // ---- l-normalize + store fp16 partial image [half][b][qt][64r][16chunk]
    if (g == 0) {
        ((float*)Pw)[c15] = lrow;
        ML[half * 32768 + b * 2048 + qt * 64 + w * 16 + c15] = lrow;
    }
    float linv[4];
    #pragma unroll
    for (int r = 0; r < 4; ++r) linv[r] = 1.f / ((float*)Pw)[4 * g + r];
    u16* vout = VOI + (long)half * 4194304 + ((long)b * 32 + qt) * 8192;
    #pragma unroll
    for (int r = 0; r < 4; ++r) {
        int rowl = w * 16 + 4 * g + r;
        int rsw = (4 * g + r) & 7;
        #pragma unroll
        for (int dt = 0; dt < 7; ++dt) {
            int d = dt * 16 + c15;
            int pos = rowl * 128 + ((((d >> 3) ^ rsw) << 3) | (d & 7));
            vout[pos] = h2b((_Float16)(O[dt][r] * linv[r]));
        }
    }
}

// ---------------- h = relu(VO@W2 + d1_b) via MFMA; fused half-combine ------
__global__ __launch_bounds__(256) void k_hpool(
    const u16* __restrict__ VOI, const float* __restrict__ ML,
    const u16* __restrict__ W2F, const float* __restrict__ d1b,
    float* __restrict__ pmax, float* __restrict__ psum) {
    __shared__ __align__(16) u16 A[8192];
    __shared__ float redM[4][400], redS[4][400];
    __shared__ float wgt[64][2];
    const int tid = threadIdx.x;
    const int w = tid >> 6, l = tid & 63, g = l >> 4, c15 = l & 15;
    const int b = blockIdx.y, rt = blockIdx.x;

    if (tid < 64) {
        float a = ML[b * 2048 + rt * 64 + tid];
        float c = ML[32768 + b * 2048 + rt * 64 + tid];
        float inv = 1.f / (a + c);
        wgt[tid][0] = a * inv;
        wgt[tid][1] = c * inv;
    }
    __syncthreads();

    const u16* s1 = VOI + ((long)b * 32 + rt) * 8192;
    const u16* s2 = s1 + 4194304;
    #pragma unroll
    for (int r = 0; r < 4; ++r) {
        int u = tid + r * 256;
        int row = u >> 4;
        us8 p1 = *(const us8*)&s1[(long)u * 8];
        us8 p2 = *(const us8*)&s2[(long)u * 8];
        float w1 = wgt[row][0], w2 = wgt[row][1];
        us8 o;
        #pragma unroll
        for (int j = 0; j < 8; ++j)
            o[j] = h2b((_Float16)(w1 * b2f(p1[j]) + w2 * b2f(p2[j])));
        *(us8*)&A[u * 8] = o;
    }
    __syncthreads();

    const int arow = w * 16 + c15;
    f16x8 af[4];
    #pragma unroll
    for (int ks = 0; ks < 4; ++ks)
        af[ks] = *(const f16x8*)&A[arow * 128 + ((ks * 32 + g * 8) ^ ((arow & 7) << 3))];

    for (int nt = 0; nt < 25; ++nt) {
        f4v acc = (f4v){0.f, 0.f, 0.f, 0.f};
        #pragma unroll
        for (int ks = 0; ks < 4; ++ks) {
            f16x8 bf = *(const f16x8*)&W2F[(nt * 4 + ks) * 512 + l * 8];
            acc = __builtin_amdgcn_mfma_f32_16x16x32_f16(af[ks], bf, acc, 0, 0, 0);
        }
        float bias = d1b[nt * 16 + c15];
        float mx4 = -1e30f, sm4 = 0.f;
        #pragma unroll
        for (int r = 0; r < 4; ++r) {
            float h = fmaxf(acc[r] + bias, 0.f);
            mx4 = fmaxf(mx4, h);
            sm4 += h;
        }
        mx4 = fmaxf(mx4, __shfl_xor(mx4, 16));
        mx4 = fmaxf(mx4, __shfl_xor(mx4, 32));
        sm4 += __shfl_xor(sm4, 16);
        sm4 += __shfl_xor(sm4, 32);
        if (g == 0) {
            redM[w][nt * 16 + c15] = mx4;
            redS[w][nt * 16 + c15] = sm4;
        }
    }
    __syncthreads();
    for (int j = tid; j < 400; j += 256) {
        float mx = fmaxf(fmaxf(redM[0][j], redM[1][j]), fmaxf(redM[2][j], redM[3][j]));
        float sm = redS[0][j] + redS[1][j] + redS[2][j] + redS[3][j];
        pmax[((long)b * 32 + rt) * 400 + j] = mx;
        psum[((long)b * 32 + rt) * 400 + j] = sm;
    }
}

// ---------------- reduce partials -> pooled[b][800] ------------------------
__global__ void k_pred(const float* __restrict__ pmax, const float* __restrict__ psum,
                       float* __restrict__ pooled) {
    const int b = blockIdx.x;
    for (int j = threadIdx.x; j < 400; j += 256) {
        float mx = -1e30f, sm = 0.f;
        for (int t = 0; t < 32; ++t) {
            mx = fmaxf(mx, pmax[((long)b * 32 + t) * 400 + j]);
            sm += psum[((long)b * 32 + t) * 400 + j];
        }
        pooled[b * 800 + j] = mx;
        pooled[b * 800 + 400 + j] = sm * (1.f / 2048.f);
    }
}

// ---------------- fc1 / fc2 ------------------------------------------------
__global__ void k_fc1(const float* __restrict__ pooled, const float* __restrict__ w,
                      const float* __restrict__ bias, float* __restrict__ out) {
    const int b = blockIdx.x, j = threadIdx.x;
    float acc = bias[j];
    for (int k = 0; k < 800; ++k) acc += pooled[b * 800 + k] * w[k * 512 + j];
    out[b * 512 + j] = fmaxf(acc, 0.f);
}

__global__ void k_fc2(const float* __restrict__ h, const float* __restrict__ w,
                      const float* __restrict__ bias, float* __restrict__ out) {
    const int b = blockIdx.x, j = threadIdx.x;
    float acc = bias[j];
    for (int k = 0; k < 512; ++k) acc += h[b * 512 + k] * w[k * 256 + j];
    out[b * 256 + j] = fmaxf(acc, 0.f);
}

extern "C" void kernel_launch(void* const* d_in, const int* in_sizes, int n_in,
                              void* d_out, int out_size, void* d_ws, size_t ws_size,
                              hipStream_t stream) {
    const float* x          = (const float*)d_in[0];
    const float* attn_kernel= (const float*)d_in[1];
    const float* attn_dense = (const float*)d_in[2];
    const float* d1_w       = (const float*)d_in[3];
    const float* d1_b       = (const float*)d_in[4];
    const float* fc1_w      = (const float*)d_in[5];
    const float* fc1_b      = (const float*)d_in[6];
    const float* fc2_w      = (const float*)d_in[7];
    const float* fc2_b      = (const float*)d_in[8];
    float* out = (float*)d_out;
    char*  wsb = (char*)d_ws;

    // ws layout (bytes), total ~45.6 MB
    u16*    QH   = (u16*)(wsb);                    //  8,388,608
    u16*    KH   = (u16*)(wsb + 8388608);          //  8,388,608 (tile images)
    u16*    VT   = (u16*)(wsb + 16777216);         //  8,388,608 (tile images)
    u16*    VOI  = (u16*)(wsb + 25165824);         // 16,777,216 (2 half-images)
    u16*    WSP  = (u16*)(wsb + 41943040);         //    638,976
    u16*    W2F  = (u16*)(wsb + 42582016);         //    102,400
    float*  ADF  = (float*)(wsb + 42684416);       //    160,000
    float*  PMAX = (float*)(wsb + 42844416);       //    819,200
    float*  PSUM = (float*)(wsb + 43663616);       //    819,200
    float*  POOL = (float*)(wsb + 44482816);       //     51,200
    float*  FC1  = (float*)(wsb + 44534016);       //     32,768
    float*  ML   = (float*)(wsb + 44566784);       //    262,144
    float*  W2P  = (float*)(wsb + 44828928);       //    819,200

    k_wprep<<<624, 256, 0, stream>>>(attn_kernel, WSP);
    k_fold<<<157, 256, 0, stream>>>(attn_dense, ADF);
    k_w2p <<<dim3(200, 4), 256, 0, stream>>>(ADF, d1_w, W2P);
    k_w2r <<<200, 256, 0, stream>>>(W2P, W2F);
    k_gemm_qkv<<<1536, 256, 0, stream>>>(x, WSP, QH, KH, VT);
    k_flash<<<dim3(32, 16, 2), 256, 0, stream>>>(QH, KH, VT, VOI, ML);
    k_hpool<<<dim3(32, 16), 256, 0, stream>>>(VOI, ML, W2F, d1_b, PMAX, PSUM);
    k_pred<<<16, 256, 0, stream>>>(PMAX, PSUM, POOL);
    k_fc1 <<<16, 512, 0, stream>>>(POOL, fc1_w, fc1_b, FC1);
    k_fc2 <<<16, 256, 0, stream>>>(FC1, fc2_w, fc2_b, out);
}